// Round 5
// baseline (897.985 us; speedup 1.0000x reference)
//
#include <hip/hip_runtime.h>
#include <hip/hip_bf16.h>

// Problem constants (match reference)
#define NN     20000
#define ERAW   320000
#define ETOT   (ERAW + NN)   // 340000 with self loops
#define F_IN   50
#define HID    64
#define HEADS  8
#define WIDTH  512           // HID*HEADS
#define NCLS   121
#define NCLS_P 128           // padded cols for layer-3 MFMA GEMM

typedef __attribute__((ext_vector_type(8))) __bf16 bf16x8;
typedef __attribute__((ext_vector_type(4))) float floatx4;

// ---------------- fp32 -> bf16 split helpers --------------------------------
__device__ __forceinline__ unsigned short f32_to_bf16_rn(float f) {
  unsigned u = __float_as_uint(f);
  unsigned r = u + 0x7fffu + ((u >> 16) & 1u);
  return (unsigned short)(r >> 16);
}
__device__ __forceinline__ void split_one(float f, unsigned short& h,
                                          unsigned short& l) {
  h = f32_to_bf16_rn(f);
  float fh = __uint_as_float(((unsigned)h) << 16);
  l = f32_to_bf16_rn(f - fh);
}

__global__ __launch_bounds__(256) void split_hi_lo4(
    const float4* __restrict__ A, ushort4* __restrict__ hi,
    ushort4* __restrict__ lo, int total4) {
  int i = blockIdx.x * blockDim.x + threadIdx.x;
  if (i >= total4) return;
  float4 f = A[i];
  ushort4 h, l;
  split_one(f.x, h.x, l.x);
  split_one(f.y, h.y, l.y);
  split_one(f.z, h.z, l.z);
  split_one(f.w, h.w, l.w);
  hi[i] = h;
  lo[i] = l;
}

// W [K][M] fp32 -> Bt hi/lo [Mp][K] bf16 ushort (rows m>=M zero-padded)
__global__ __launch_bounds__(256) void transpose_split(
    const float* __restrict__ W, unsigned short* __restrict__ thi,
    unsigned short* __restrict__ tlo, int K, int M, int Mp) {
  __shared__ float t[32][33];
  int k0 = blockIdx.x * 32, m0 = blockIdx.y * 32;
  int tx = threadIdx.x & 31, ty = threadIdx.x >> 5;  // 32 x 8
  #pragma unroll
  for (int r = 0; r < 4; ++r) {
    int k = k0 + ty + r * 8, m = m0 + tx;
    float v = 0.f;
    if (k < K && m < M) v = W[(size_t)k * M + m];
    t[ty + r * 8][tx] = v;
  }
  __syncthreads();
  #pragma unroll
  for (int r = 0; r < 4; ++r) {
    int m = m0 + ty + r * 8, k = k0 + tx;
    if (m < Mp && k < K) {
      unsigned short h, l;
      split_one(t[tx][ty + r * 8], h, l);
      thi[(size_t)m * K + k] = h;
      tlo[(size_t)m * K + k] = l;
    }
  }
}

// ---- split-bf16 MFMA GEMM: C[N,M] = A[N,K] @ B[K,M] (B given as Bt[Mp][K]) -
__global__ __launch_bounds__(256) void gemm_mfma_split(
    const unsigned short* __restrict__ Ahi, const unsigned short* __restrict__ Alo,
    const unsigned short* __restrict__ Bthi, const unsigned short* __restrict__ Btlo,
    float* __restrict__ C, int N, int K, int M) {
  __shared__ unsigned short sAhi[4096], sAlo[4096], sBhi[4096], sBlo[4096];
  const int tid = threadIdx.x;
  const int wave = tid >> 6, lane = tid & 63;
  const int wr = wave >> 1, wc = wave & 1;
  const int r0 = blockIdx.y * 128;
  const int c0 = blockIdx.x * 128;
  const int lkg = lane >> 4;
  const int lmn = lane & 15;

  const int skg = tid & 3;
  const int srow = tid >> 2;
  int ra0 = r0 + srow;        if (ra0 > NN - 1) ra0 = NN - 1;
  int ra1 = r0 + srow + 64;   if (ra1 > NN - 1) ra1 = NN - 1;
  const unsigned short* gAhi0 = Ahi + (size_t)ra0 * K + skg * 8;
  const unsigned short* gAhi1 = Ahi + (size_t)ra1 * K + skg * 8;
  const unsigned short* gAlo0 = Alo + (size_t)ra0 * K + skg * 8;
  const unsigned short* gAlo1 = Alo + (size_t)ra1 * K + skg * 8;
  const unsigned short* gBhi0 = Bthi + (size_t)(c0 + srow) * K + skg * 8;
  const unsigned short* gBhi1 = Bthi + (size_t)(c0 + srow + 64) * K + skg * 8;
  const unsigned short* gBlo0 = Btlo + (size_t)(c0 + srow) * K + skg * 8;
  const unsigned short* gBlo1 = Btlo + (size_t)(c0 + srow + 64) * K + skg * 8;

  floatx4 acc[4][4] = {};

  uint4 a0, a1, a2, a3, b0, b1, b2, b3;
  auto gload = [&](int kk) {
    a0 = *(const uint4*)(gAhi0 + kk);
    a1 = *(const uint4*)(gAhi1 + kk);
    a2 = *(const uint4*)(gAlo0 + kk);
    a3 = *(const uint4*)(gAlo1 + kk);
    b0 = *(const uint4*)(gBhi0 + kk);
    b1 = *(const uint4*)(gBhi1 + kk);
    b2 = *(const uint4*)(gBlo0 + kk);
    b3 = *(const uint4*)(gBlo1 + kk);
  };
  gload(0);

  const int w0 = (skg * 128 + srow) * 8;
  const int w1 = (skg * 128 + srow + 64) * 8;

  for (int k0 = 0; k0 < K; k0 += 32) {
    __syncthreads();
    *(uint4*)(sAhi + w0) = a0;
    *(uint4*)(sAhi + w1) = a1;
    *(uint4*)(sAlo + w0) = a2;
    *(uint4*)(sAlo + w1) = a3;
    *(uint4*)(sBhi + w0) = b0;
    *(uint4*)(sBhi + w1) = b1;
    *(uint4*)(sBlo + w0) = b2;
    *(uint4*)(sBlo + w1) = b3;
    __syncthreads();
    if (k0 + 32 < K) gload(k0 + 32);

    bf16x8 fAhi[4], fAlo[4], fBhi[4], fBlo[4];
    #pragma unroll
    for (int mi = 0; mi < 4; ++mi) {
      int m = wr * 64 + mi * 16 + lmn;
      fAhi[mi] = *(const bf16x8*)(sAhi + (lkg * 128 + m) * 8);
      fAlo[mi] = *(const bf16x8*)(sAlo + (lkg * 128 + m) * 8);
    }
    #pragma unroll
    for (int ni = 0; ni < 4; ++ni) {
      int n = wc * 64 + ni * 16 + lmn;
      fBhi[ni] = *(const bf16x8*)(sBhi + (lkg * 128 + n) * 8);
      fBlo[ni] = *(const bf16x8*)(sBlo + (lkg * 128 + n) * 8);
    }
    #pragma unroll
    for (int mi = 0; mi < 4; ++mi)
      #pragma unroll
      for (int ni = 0; ni < 4; ++ni) {
        acc[mi][ni] = __builtin_amdgcn_mfma_f32_16x16x32_bf16(
            fAhi[mi], fBhi[ni], acc[mi][ni], 0, 0, 0);
        acc[mi][ni] = __builtin_amdgcn_mfma_f32_16x16x32_bf16(
            fAhi[mi], fBlo[ni], acc[mi][ni], 0, 0, 0);
        acc[mi][ni] = __builtin_amdgcn_mfma_f32_16x16x32_bf16(
            fAlo[mi], fBhi[ni], acc[mi][ni], 0, 0, 0);
      }
  }

  #pragma unroll
  for (int mi = 0; mi < 4; ++mi) {
    #pragma unroll
    for (int r = 0; r < 4; ++r) {
      int grow = r0 + wr * 64 + mi * 16 + (lane >> 4) * 4 + r;
      if (grow >= N) continue;
      #pragma unroll
      for (int ni = 0; ni < 4; ++ni) {
        int gcol = c0 + wc * 64 + ni * 16 + lmn;
        if (gcol < M) C[(size_t)grow * M + gcol] = acc[mi][ni][r];
      }
    }
  }
}

// ---------------- layer-1 folded attention weights --------------------------
// w1as[k*8+h] = sum_c W1[k, h*64+c] * a1_src[h, c]  (same for dst)
__global__ __launch_bounds__(256) void fold_w1a(
    const float* __restrict__ W1, const float* __restrict__ a1s,
    const float* __restrict__ a1d, float* __restrict__ w1as,
    float* __restrict__ w1ad) {
  int idx = blockIdx.x * blockDim.x + threadIdx.x;
  if (idx >= 2 * F_IN * HEADS) return;
  int which = idx >= F_IN * HEADS;
  int r = which ? idx - F_IN * HEADS : idx;
  int k = r >> 3, h = r & 7;
  const float* a = which ? a1d : a1s;
  float s = 0.f;
  for (int c = 0; c < HID; ++c) s += W1[(size_t)k * WIDTH + h * HID + c] * a[h * HID + c];
  (which ? w1ad : w1as)[r] = s;
}

// al1[n,h] = sum_k x[n,k] * w1a[k,h]   (one wave per node)
__global__ __launch_bounds__(256) void al1_kernel(
    const float* __restrict__ x, const float* __restrict__ w1as,
    const float* __restrict__ w1ad, float* __restrict__ al_s,
    float* __restrict__ al_d) {
  int n = (blockIdx.x * blockDim.x + threadIdx.x) >> 6;
  int lane = threadIdx.x & 63;
  if (n >= NN) return;
  float xv = (lane < F_IN) ? x[(size_t)n * F_IN + lane] : 0.f;
  float ws[HEADS], wd[HEADS];
  #pragma unroll
  for (int h = 0; h < HEADS; ++h) {
    ws[h] = (lane < F_IN) ? w1as[lane * HEADS + h] : 0.f;
    wd[h] = (lane < F_IN) ? w1ad[lane * HEADS + h] : 0.f;
  }
  #pragma unroll
  for (int h = 0; h < HEADS; ++h) {
    float ss = xv * ws[h], sd = xv * wd[h];
    #pragma unroll
    for (int o = 32; o; o >>= 1) {
      ss += __shfl_xor(ss, o);
      sd += __shfl_xor(sd, o);
    }
    if (lane == 0) {
      al_s[n * HEADS + h] = ss;
      al_d[n * HEADS + h] = sd;
    }
  }
}

// ---------------- per-node attention logits (from h; H=1 layers) -----------
__global__ __launch_bounds__(256) void compute_al(
    const float* __restrict__ h, const float* __restrict__ a_src,
    const float* __restrict__ a_dst, float* __restrict__ al_s,
    float* __restrict__ al_d, int Nn, int H, int C) {
  int wave = (blockIdx.x * blockDim.x + threadIdx.x) >> 6;
  int lane = threadIdx.x & 63;
  if (wave >= Nn) return;
  const float* hr = h + (size_t)wave * H * C;
  for (int hd = 0; hd < H; ++hd) {
    float ss = 0.f, sd = 0.f;
    for (int c = lane; c < C; c += 64) {
      float v = hr[hd * C + c];
      ss += v * a_src[hd * C + c];
      sd += v * a_dst[hd * C + c];
    }
    #pragma unroll
    for (int o = 32; o; o >>= 1) {
      ss += __shfl_xor(ss, o);
      sd += __shfl_xor(sd, o);
    }
    if (lane == 0) {
      al_s[wave * H + hd] = ss;
      al_d[wave * H + hd] = sd;
    }
  }
}

// ---------------- CSR build (once; shared by all layers) --------------------
__global__ __launch_bounds__(256) void count_deg(
    const int* __restrict__ edst, int* __restrict__ deg) {
  int e = blockIdx.x * blockDim.x + threadIdx.x;
  if (e >= ETOT) return;
  int d = (e < ERAW) ? edst[e] : (e - ERAW);
  atomicAdd(&deg[d], 1);
}

__global__ __launch_bounds__(256) void scan_deg(
    const int* __restrict__ deg, int* __restrict__ rowptr) {
  __shared__ int part[256];
  const int t = threadIdx.x;
  const int CHUNK = (NN + 255) / 256;
  int lo = t * CHUNK, hi = min(lo + CHUNK, NN);
  int s = 0;
  for (int i = lo; i < hi; ++i) s += deg[i];
  part[t] = s;
  __syncthreads();
  for (int off = 1; off < 256; off <<= 1) {
    int v = (t >= off) ? part[t - off] : 0;
    __syncthreads();
    part[t] += v;
    __syncthreads();
  }
  int base = (t == 0) ? 0 : part[t - 1];
  for (int i = lo; i < hi; ++i) {
    rowptr[i] = base;
    base += deg[i];
  }
  if (t == 255) rowptr[NN] = part[255];
}

__global__ __launch_bounds__(256) void scatter_csr(
    const int* __restrict__ esrc, const int* __restrict__ edst,
    const int* __restrict__ rowptr, int* __restrict__ cnt,
    int* __restrict__ csrc) {
  int e = blockIdx.x * blockDim.x + threadIdx.x;
  if (e >= ETOT) return;
  int s, d;
  if (e < ERAW) { s = esrc[e]; d = edst[e]; }
  else          { s = e - ERAW; d = e - ERAW; }
  int pos = rowptr[d] + atomicAdd(&cnt[d], 1);
  csrc[pos] = s;
}

// ---- CSR-order edge softmax: alpha[p*H+h] = normalized attention ----------
// One wave per destination node; al gathers are L2-resident (<=640 KB).
template <int H>
__global__ __launch_bounds__(256) void csr_softmax(
    const int* __restrict__ rowptr, const int* __restrict__ csrc,
    const float* __restrict__ al_s, const float* __restrict__ al_d,
    float* __restrict__ alpha) {
  const int w = threadIdx.x >> 6, lane = threadIdx.x & 63;
  const int d = blockIdx.x * 4 + w;
  if (d >= NN) return;
  const int r0 = rowptr[d], r1 = rowptr[d + 1];
  float ald[H];
  #pragma unroll
  for (int h = 0; h < H; ++h) ald[h] = al_d[d * H + h];

  float mx[H];
  #pragma unroll
  for (int h = 0; h < H; ++h) mx[h] = -3.4e38f;
  for (int p = r0 + lane; p < r1; p += 64) {
    int s = csrc[p];
    #pragma unroll
    for (int h = 0; h < H; ++h) {
      float v = al_s[s * H + h] + ald[h];
      v = (v > 0.f) ? v : 0.2f * v;
      mx[h] = fmaxf(mx[h], v);
    }
  }
  #pragma unroll
  for (int o = 32; o; o >>= 1)
    #pragma unroll
    for (int h = 0; h < H; ++h) mx[h] = fmaxf(mx[h], __shfl_xor(mx[h], o));

  float zs[H];
  #pragma unroll
  for (int h = 0; h < H; ++h) zs[h] = 0.f;
  for (int p = r0 + lane; p < r1; p += 64) {
    int s = csrc[p];
    #pragma unroll
    for (int h = 0; h < H; ++h) {
      float v = al_s[s * H + h] + ald[h];
      v = (v > 0.f) ? v : 0.2f * v;
      float e = __expf(v - mx[h]);
      alpha[(size_t)p * H + h] = e;
      zs[h] += e;
    }
  }
  #pragma unroll
  for (int o = 32; o; o >>= 1)
    #pragma unroll
    for (int h = 0; h < H; ++h) zs[h] += __shfl_xor(zs[h], o);
  float iz[H];
  #pragma unroll
  for (int h = 0; h < H; ++h) iz[h] = 1.0f / (zs[h] + 1e-16f);

  for (int p = r0 + lane; p < r1; p += 64) {
    #pragma unroll
    for (int h = 0; h < H; ++h) alpha[(size_t)p * H + h] *= iz[h];
  }
}

// ---- layer-1: aggregate raw x per head: aggx[d, h*50+k] -------------------
__global__ __launch_bounds__(256) void agg_x(
    const int* __restrict__ rowptr, const int* __restrict__ csrc,
    const float* __restrict__ alpha, const float* __restrict__ x,
    float* __restrict__ aggx) {
  const int w = threadIdx.x >> 6, lane = threadIdx.x & 63;
  const int d = blockIdx.x * 4 + w;
  if (d >= NN) return;
  const int r0 = rowptr[d], r1 = rowptr[d + 1];
  float acc[HEADS];
  #pragma unroll
  for (int h = 0; h < HEADS; ++h) acc[h] = 0.f;
  for (int p = r0; p < r1; ++p) {
    int s = csrc[p];
    float av = alpha[(size_t)p * HEADS + (lane & 7)];
    float xv = (lane < F_IN) ? x[(size_t)s * F_IN + lane] : 0.f;
    #pragma unroll
    for (int h = 0; h < HEADS; ++h) acc[h] += __shfl(av, h, 8) * xv;
  }
  if (lane < F_IN) {
    #pragma unroll
    for (int h = 0; h < HEADS; ++h)
      aggx[(size_t)d * (HEADS * F_IN) + h * F_IN + lane] = acc[h];
  }
}

// ---- layer-1 block-diagonal GEMM + bias + ELU -> out [NN, 512] ------------
// out[n, head*64+c] = elu( sum_k aggx[n, head*50+k] * W1[k, head*64+c] + b1 )
__global__ __launch_bounds__(256) void gemm_l1(
    const float* __restrict__ aggx, const float* __restrict__ W1,
    const float* __restrict__ b1, float* __restrict__ out) {
  __shared__ float As[16][64 + 1];
  __shared__ float Bs[16][64 + 1];
  const int tid = threadIdx.x;
  const int tx = tid & 15, ty = tid >> 4;
  const int row0 = blockIdx.x * 64;
  const int head = blockIdx.y;
  float acc[4][4] = {};
  for (int k0 = 0; k0 < F_IN; k0 += 16) {
    #pragma unroll
    for (int i = 0; i < 4; ++i) {
      int r = (tid >> 4) + i * 16;
      int kk = tid & 15;
      int gr = row0 + r, gk = k0 + kk;
      float v = 0.f;
      if (gr < NN && gk < F_IN)
        v = aggx[(size_t)gr * (HEADS * F_IN) + head * F_IN + gk];
      As[kk][r] = v;
    }
    #pragma unroll
    for (int i = 0; i < 4; ++i) {
      int r = (tid >> 6) + i * 4;
      int c = tid & 63;
      int gk = k0 + r;
      float v = 0.f;
      if (gk < F_IN) v = W1[(size_t)gk * WIDTH + head * HID + c];
      Bs[r][c] = v;
    }
    __syncthreads();
    #pragma unroll
    for (int kk = 0; kk < 16; ++kk) {
      float a[4], b[4];
      #pragma unroll
      for (int i = 0; i < 4; ++i) a[i] = As[kk][ty * 4 + i];
      #pragma unroll
      for (int j = 0; j < 4; ++j) b[j] = Bs[kk][tx * 4 + j];
      #pragma unroll
      for (int i = 0; i < 4; ++i)
        #pragma unroll
        for (int j = 0; j < 4; ++j) acc[i][j] += a[i] * b[j];
    }
    __syncthreads();
  }
  #pragma unroll
  for (int i = 0; i < 4; ++i) {
    int gr = row0 + ty * 4 + i;
    if (gr >= NN) continue;
    #pragma unroll
    for (int j = 0; j < 4; ++j) {
      int gc = head * HID + tx * 4 + j;
      float v = acc[i][j] + b1[gc];
      v = (v > 0.f) ? v : expm1f(v);
      out[(size_t)gr * WIDTH + gc] = v;
    }
  }
}

// ---- pull aggregation (H=1): alpha pre-normalized, CSR order --------------
template <int M, bool ELU>
__global__ __launch_bounds__(256) void pull_agg(
    const int* __restrict__ rowptr, const int* __restrict__ csrc,
    const float* __restrict__ alpha, const float* __restrict__ h,
    const float* __restrict__ bias, float* __restrict__ out) {
  constexpr int EPL = (M + 63) / 64;
  const int w = threadIdx.x >> 6;
  const int lane = threadIdx.x & 63;
  const int d = blockIdx.x * 4 + w;
  if (d >= NN) return;
  const int r0 = rowptr[d], r1 = rowptr[d + 1];
  const int base = lane * EPL;

  float acc[EPL];
  #pragma unroll
  for (int j = 0; j < EPL; ++j) acc[j] = 0.f;
  for (int p = r0; p < r1; ++p) {
    int s = csrc[p];
    float a = alpha[p];
    const float* hr = h + (size_t)s * M + base;
    #pragma unroll
    for (int j = 0; j < EPL; ++j) {
      if ((M % 64 == 0) || (base + j < M)) acc[j] += hr[j] * a;
    }
  }

  float* od = out + (size_t)d * M + base;
  #pragma unroll
  for (int j = 0; j < EPL; ++j) {
    if ((M % 64 == 0) || (base + j < M)) {
      float v = acc[j] + bias[base + j];
      if (ELU) v = (v > 0.f) ? v : expm1f(v);
      od[j] = v;
    }
  }
}

extern "C" void kernel_launch(void* const* d_in, const int* in_sizes, int n_in,
                              void* d_out, int out_size, void* d_ws,
                              size_t ws_size, hipStream_t stream) {
  const float* x      = (const float*)d_in[0];
  const int*   ei     = (const int*)d_in[1];
  const float* W1     = (const float*)d_in[2];
  const float* a1_src = (const float*)d_in[3];
  const float* a1_dst = (const float*)d_in[4];
  const float* b1     = (const float*)d_in[5];
  const float* W2     = (const float*)d_in[6];
  const float* a2_src = (const float*)d_in[7];
  const float* a2_dst = (const float*)d_in[8];
  const float* b2     = (const float*)d_in[9];
  const float* W3     = (const float*)d_in[10];
  const float* a3_src = (const float*)d_in[11];
  const float* a3_dst = (const float*)d_in[12];
  const float* b3     = (const float*)d_in[13];
  float* out = (float*)d_out;

  const int* esrc = ei;
  const int* edst = ei + ERAW;

  // Workspace carve-up
  unsigned short* aHi  = (unsigned short*)d_ws;           // NN*WIDTH
  unsigned short* aLo  = aHi + (size_t)NN * WIDTH;
  unsigned short* w2tHi = aLo + (size_t)NN * WIDTH;       // 512*512
  unsigned short* w2tLo = w2tHi + (size_t)WIDTH * WIDTH;
  unsigned short* w3tHi = w2tLo + (size_t)WIDTH * WIDTH;  // 128*512
  unsigned short* w3tLo = w3tHi + (size_t)NCLS_P * WIDTH;
  float* bufA   = (float*)(w3tLo + (size_t)NCLS_P * WIDTH);  // NN*WIDTH
  float* bufB   = bufA + (size_t)NN * WIDTH;
  float* alpha  = bufB + (size_t)NN * WIDTH;              // ETOT*HEADS
  float* al_s   = alpha + (size_t)ETOT * HEADS;
  float* al_d   = al_s + (size_t)NN * HEADS;
  float* w1as   = al_d + (size_t)NN * HEADS;              // 50*8
  float* w1ad   = w1as + F_IN * HEADS;
  int* deg      = (int*)(w1ad + F_IN * HEADS);
  int* rowptr   = deg + NN;
  int* cnt      = rowptr + NN + 4;
  int* csrc     = cnt + NN;                               // ETOT
  float* aggx   = bufA;  // alias: bufA free during layer 1 (20000*400 < 20000*512)

  // ---- build CSR by destination (once) ----
  hipMemsetAsync(deg, 0, (size_t)NN * sizeof(int), stream);
  hipMemsetAsync(cnt, 0, (size_t)NN * sizeof(int), stream);
  const int eblk = (ETOT + 255) / 256;
  count_deg<<<eblk, 256, 0, stream>>>(edst, deg);
  scan_deg<<<1, 256, 0, stream>>>(deg, rowptr);
  scatter_csr<<<eblk, 256, 0, stream>>>(esrc, edst, rowptr, cnt, csrc);

  // ---- weight transpose+split (once) ----
  transpose_split<<<dim3(WIDTH / 32, WIDTH / 32), 256, 0, stream>>>(
      W2, w2tHi, w2tLo, WIDTH, WIDTH, WIDTH);
  transpose_split<<<dim3(WIDTH / 32, NCLS_P / 32), 256, 0, stream>>>(
      W3, w3tHi, w3tLo, WIDTH, NCLS, NCLS_P);

  const int nwblk = (NN + 3) / 4;
  const int splitblk = ((NN * WIDTH / 4) + 255) / 256;

  // ---- Layer 1 (aggregate-x-first): never materializes h1 ----
  {
    fold_w1a<<<(2 * F_IN * HEADS + 255) / 256, 256, 0, stream>>>(
        W1, a1_src, a1_dst, w1as, w1ad);
    al1_kernel<<<nwblk, 256, 0, stream>>>(x, w1as, w1ad, al_s, al_d);
    csr_softmax<HEADS><<<nwblk, 256, 0, stream>>>(rowptr, csrc, al_s, al_d,
                                                  alpha);
    agg_x<<<nwblk, 256, 0, stream>>>(rowptr, csrc, alpha, x, aggx);
    gemm_l1<<<dim3((NN + 63) / 64, HEADS), 256, 0, stream>>>(aggx, W1, b1,
                                                             bufB);
  }
  // ---- Layer 2: bufB @ W2 -> h2(bufA) via split-bf16 MFMA ----
  {
    split_hi_lo4<<<splitblk, 256, 0, stream>>>((const float4*)bufB,
                                               (ushort4*)aHi, (ushort4*)aLo,
                                               NN * WIDTH / 4);
    gemm_mfma_split<<<dim3(WIDTH / 128, (NN + 127) / 128), 256, 0, stream>>>(
        aHi, aLo, w2tHi, w2tLo, bufA, NN, WIDTH, WIDTH);
    compute_al<<<nwblk, 256, 0, stream>>>(bufA, a2_src, a2_dst, al_s, al_d,
                                          NN, 1, WIDTH);
    csr_softmax<1><<<nwblk, 256, 0, stream>>>(rowptr, csrc, al_s, al_d,
                                              alpha);
    pull_agg<WIDTH, true><<<nwblk, 256, 0, stream>>>(rowptr, csrc, alpha,
                                                     bufA, b2, bufB);
  }
  // ---- Layer 3: bufB @ W3 -> h3(bufA); agg -> out (no ELU) ----
  {
    split_hi_lo4<<<splitblk, 256, 0, stream>>>((const float4*)bufB,
                                               (ushort4*)aHi, (ushort4*)aLo,
                                               NN * WIDTH / 4);
    gemm_mfma_split<<<dim3(NCLS_P / 128, (NN + 127) / 128), 256, 0, stream>>>(
        aHi, aLo, w3tHi, w3tLo, bufA, NN, WIDTH, NCLS);
    compute_al<<<nwblk, 256, 0, stream>>>(bufA, a3_src, a3_dst, al_s, al_d,
                                          NN, 1, NCLS);
    csr_softmax<1><<<nwblk, 256, 0, stream>>>(rowptr, csrc, al_s, al_d,
                                              alpha);
    pull_agg<NCLS, false><<<nwblk, 256, 0, stream>>>(rowptr, csrc, alpha,
                                                     bufA, b3, out);
  }
}

// Round 6
// 635.717 us; speedup vs baseline: 1.4126x; 1.4126x over previous
//
#include <hip/hip_runtime.h>
#include <hip/hip_bf16.h>

// Problem constants (match reference)
#define NN     20000
#define ERAW   320000
#define ETOT   (ERAW + NN)   // 340000 with self loops
#define F_IN   50
#define HID    64
#define HEADS  8
#define WIDTH  512           // HID*HEADS
#define NCLS   121
#define NCLS_P 128           // padded cols for layer-3 MFMA GEMM

typedef __attribute__((ext_vector_type(8))) __bf16 bf16x8;
typedef __attribute__((ext_vector_type(4))) float floatx4;

// ---------------- fp32 -> bf16 split helpers --------------------------------
__device__ __forceinline__ unsigned short f32_to_bf16_rn(float f) {
  unsigned u = __float_as_uint(f);
  unsigned r = u + 0x7fffu + ((u >> 16) & 1u);
  return (unsigned short)(r >> 16);
}
__device__ __forceinline__ void split_one(float f, unsigned short& h,
                                          unsigned short& l) {
  h = f32_to_bf16_rn(f);
  float fh = __uint_as_float(((unsigned)h) << 16);
  l = f32_to_bf16_rn(f - fh);
}

__global__ __launch_bounds__(256) void split_hi_lo4(
    const float4* __restrict__ A, ushort4* __restrict__ hi,
    ushort4* __restrict__ lo, int total4) {
  int i = blockIdx.x * blockDim.x + threadIdx.x;
  if (i >= total4) return;
  float4 f = A[i];
  ushort4 h, l;
  split_one(f.x, h.x, l.x);
  split_one(f.y, h.y, l.y);
  split_one(f.z, h.z, l.z);
  split_one(f.w, h.w, l.w);
  hi[i] = h;
  lo[i] = l;
}

// W [K][M] fp32 -> Bt hi/lo [Mp][K] bf16 ushort (rows m>=M zero-padded)
__global__ __launch_bounds__(256) void transpose_split(
    const float* __restrict__ W, unsigned short* __restrict__ thi,
    unsigned short* __restrict__ tlo, int K, int M, int Mp) {
  __shared__ float t[32][33];
  int k0 = blockIdx.x * 32, m0 = blockIdx.y * 32;
  int tx = threadIdx.x & 31, ty = threadIdx.x >> 5;  // 32 x 8
  #pragma unroll
  for (int r = 0; r < 4; ++r) {
    int k = k0 + ty + r * 8, m = m0 + tx;
    float v = 0.f;
    if (k < K && m < M) v = W[(size_t)k * M + m];
    t[ty + r * 8][tx] = v;
  }
  __syncthreads();
  #pragma unroll
  for (int r = 0; r < 4; ++r) {
    int m = m0 + ty + r * 8, k = k0 + tx;
    if (m < Mp && k < K) {
      unsigned short h, l;
      split_one(t[tx][ty + r * 8], h, l);
      thi[(size_t)m * K + k] = h;
      tlo[(size_t)m * K + k] = l;
    }
  }
}

// Build block-diagonal W1 Bt[512][512]: Bt[m][kk] = W1[kk&63][m] iff
// kk>>6 == m>>6 and (kk&63) < 50, else 0.
__global__ __launch_bounds__(256) void build_w1bd_t(
    const float* __restrict__ W1, unsigned short* __restrict__ thi,
    unsigned short* __restrict__ tlo) {
  int idx = blockIdx.x * blockDim.x + threadIdx.x;
  if (idx >= WIDTH * WIDTH) return;
  int m = idx >> 9, kk = idx & 511;
  float v = 0.f;
  if ((kk >> 6) == (m >> 6) && (kk & 63) < F_IN)
    v = W1[(size_t)(kk & 63) * WIDTH + m];
  unsigned short h, l;
  split_one(v, h, l);
  thi[idx] = h;
  tlo[idx] = l;
}

// ---- split-bf16 MFMA GEMM: C[N,M] = A[N,K] @ B[K,M] (B given as Bt[Mp][K]) -
// BELU: fused v = elu(acc + bias[col]) epilogue (layer 1).
template <bool BELU>
__global__ __launch_bounds__(256) void gemm_mfma_split(
    const unsigned short* __restrict__ Ahi, const unsigned short* __restrict__ Alo,
    const unsigned short* __restrict__ Bthi, const unsigned short* __restrict__ Btlo,
    float* __restrict__ C, const float* __restrict__ bias, int N, int K, int M) {
  __shared__ unsigned short sAhi[4096], sAlo[4096], sBhi[4096], sBlo[4096];
  const int tid = threadIdx.x;
  const int wave = tid >> 6, lane = tid & 63;
  const int wr = wave >> 1, wc = wave & 1;
  const int r0 = blockIdx.y * 128;
  const int c0 = blockIdx.x * 128;
  const int lkg = lane >> 4;
  const int lmn = lane & 15;

  const int skg = tid & 3;
  const int srow = tid >> 2;
  int ra0 = r0 + srow;        if (ra0 > NN - 1) ra0 = NN - 1;
  int ra1 = r0 + srow + 64;   if (ra1 > NN - 1) ra1 = NN - 1;
  const unsigned short* gAhi0 = Ahi + (size_t)ra0 * K + skg * 8;
  const unsigned short* gAhi1 = Ahi + (size_t)ra1 * K + skg * 8;
  const unsigned short* gAlo0 = Alo + (size_t)ra0 * K + skg * 8;
  const unsigned short* gAlo1 = Alo + (size_t)ra1 * K + skg * 8;
  const unsigned short* gBhi0 = Bthi + (size_t)(c0 + srow) * K + skg * 8;
  const unsigned short* gBhi1 = Bthi + (size_t)(c0 + srow + 64) * K + skg * 8;
  const unsigned short* gBlo0 = Btlo + (size_t)(c0 + srow) * K + skg * 8;
  const unsigned short* gBlo1 = Btlo + (size_t)(c0 + srow + 64) * K + skg * 8;

  floatx4 acc[4][4] = {};

  uint4 a0, a1, a2, a3, b0, b1, b2, b3;
  auto gload = [&](int kk) {
    a0 = *(const uint4*)(gAhi0 + kk);
    a1 = *(const uint4*)(gAhi1 + kk);
    a2 = *(const uint4*)(gAlo0 + kk);
    a3 = *(const uint4*)(gAlo1 + kk);
    b0 = *(const uint4*)(gBhi0 + kk);
    b1 = *(const uint4*)(gBhi1 + kk);
    b2 = *(const uint4*)(gBlo0 + kk);
    b3 = *(const uint4*)(gBlo1 + kk);
  };
  gload(0);

  const int w0 = (skg * 128 + srow) * 8;
  const int w1 = (skg * 128 + srow + 64) * 8;

  for (int k0 = 0; k0 < K; k0 += 32) {
    __syncthreads();
    *(uint4*)(sAhi + w0) = a0;
    *(uint4*)(sAhi + w1) = a1;
    *(uint4*)(sAlo + w0) = a2;
    *(uint4*)(sAlo + w1) = a3;
    *(uint4*)(sBhi + w0) = b0;
    *(uint4*)(sBhi + w1) = b1;
    *(uint4*)(sBlo + w0) = b2;
    *(uint4*)(sBlo + w1) = b3;
    __syncthreads();
    if (k0 + 32 < K) gload(k0 + 32);

    bf16x8 fAhi[4], fAlo[4], fBhi[4], fBlo[4];
    #pragma unroll
    for (int mi = 0; mi < 4; ++mi) {
      int m = wr * 64 + mi * 16 + lmn;
      fAhi[mi] = *(const bf16x8*)(sAhi + (lkg * 128 + m) * 8);
      fAlo[mi] = *(const bf16x8*)(sAlo + (lkg * 128 + m) * 8);
    }
    #pragma unroll
    for (int ni = 0; ni < 4; ++ni) {
      int n = wc * 64 + ni * 16 + lmn;
      fBhi[ni] = *(const bf16x8*)(sBhi + (lkg * 128 + n) * 8);
      fBlo[ni] = *(const bf16x8*)(sBlo + (lkg * 128 + n) * 8);
    }
    #pragma unroll
    for (int mi = 0; mi < 4; ++mi)
      #pragma unroll
      for (int ni = 0; ni < 4; ++ni) {
        acc[mi][ni] = __builtin_amdgcn_mfma_f32_16x16x32_bf16(
            fAhi[mi], fBhi[ni], acc[mi][ni], 0, 0, 0);
        acc[mi][ni] = __builtin_amdgcn_mfma_f32_16x16x32_bf16(
            fAhi[mi], fBlo[ni], acc[mi][ni], 0, 0, 0);
        acc[mi][ni] = __builtin_amdgcn_mfma_f32_16x16x32_bf16(
            fAlo[mi], fBhi[ni], acc[mi][ni], 0, 0, 0);
      }
  }

  #pragma unroll
  for (int mi = 0; mi < 4; ++mi) {
    #pragma unroll
    for (int r = 0; r < 4; ++r) {
      int grow = r0 + wr * 64 + mi * 16 + (lane >> 4) * 4 + r;
      if (grow >= N) continue;
      #pragma unroll
      for (int ni = 0; ni < 4; ++ni) {
        int gcol = c0 + wc * 64 + ni * 16 + lmn;
        if (gcol < M) {
          float v = acc[mi][ni][r];
          if (BELU) {
            v += bias[gcol];
            v = (v > 0.f) ? v : (__expf(v) - 1.0f);
          }
          C[(size_t)grow * M + gcol] = v;
        }
      }
    }
  }
}

// ---------------- layer-1 folded attention weights --------------------------
__global__ __launch_bounds__(256) void fold_w1a(
    const float* __restrict__ W1, const float* __restrict__ a1s,
    const float* __restrict__ a1d, float* __restrict__ w1as,
    float* __restrict__ w1ad) {
  int idx = blockIdx.x * blockDim.x + threadIdx.x;
  if (idx >= 2 * F_IN * HEADS) return;
  int which = idx >= F_IN * HEADS;
  int r = which ? idx - F_IN * HEADS : idx;
  int k = r >> 3, h = r & 7;
  const float* a = which ? a1d : a1s;
  float s = 0.f;
  for (int c = 0; c < HID; ++c) s += W1[(size_t)k * WIDTH + h * HID + c] * a[h * HID + c];
  (which ? w1ad : w1as)[r] = s;
}

// al1[n,h] = sum_k x[n,k] * w1a[k,h]   (one wave per node)
__global__ __launch_bounds__(256) void al1_kernel(
    const float* __restrict__ x, const float* __restrict__ w1as,
    const float* __restrict__ w1ad, float* __restrict__ al_s,
    float* __restrict__ al_d) {
  int n = (blockIdx.x * blockDim.x + threadIdx.x) >> 6;
  int lane = threadIdx.x & 63;
  if (n >= NN) return;
  float xv = (lane < F_IN) ? x[(size_t)n * F_IN + lane] : 0.f;
  float ws[HEADS], wd[HEADS];
  #pragma unroll
  for (int h = 0; h < HEADS; ++h) {
    ws[h] = (lane < F_IN) ? w1as[lane * HEADS + h] : 0.f;
    wd[h] = (lane < F_IN) ? w1ad[lane * HEADS + h] : 0.f;
  }
  #pragma unroll
  for (int h = 0; h < HEADS; ++h) {
    float ss = xv * ws[h], sd = xv * wd[h];
    #pragma unroll
    for (int o = 32; o; o >>= 1) {
      ss += __shfl_xor(ss, o);
      sd += __shfl_xor(sd, o);
    }
    if (lane == 0) {
      al_s[n * HEADS + h] = ss;
      al_d[n * HEADS + h] = sd;
    }
  }
}

// ---------------- per-node attention logits (from h; H=1 layers) -----------
__global__ __launch_bounds__(256) void compute_al(
    const float* __restrict__ h, const float* __restrict__ a_src,
    const float* __restrict__ a_dst, float* __restrict__ al_s,
    float* __restrict__ al_d, int Nn, int H, int C) {
  int wave = (blockIdx.x * blockDim.x + threadIdx.x) >> 6;
  int lane = threadIdx.x & 63;
  if (wave >= Nn) return;
  const float* hr = h + (size_t)wave * H * C;
  for (int hd = 0; hd < H; ++hd) {
    float ss = 0.f, sd = 0.f;
    for (int c = lane; c < C; c += 64) {
      float v = hr[hd * C + c];
      ss += v * a_src[hd * C + c];
      sd += v * a_dst[hd * C + c];
    }
    #pragma unroll
    for (int o = 32; o; o >>= 1) {
      ss += __shfl_xor(ss, o);
      sd += __shfl_xor(sd, o);
    }
    if (lane == 0) {
      al_s[wave * H + hd] = ss;
      al_d[wave * H + hd] = sd;
    }
  }
}

// ---------------- CSR build (once; shared by all layers) --------------------
__global__ __launch_bounds__(256) void count_deg(
    const int* __restrict__ edst, int* __restrict__ deg) {
  int e = blockIdx.x * blockDim.x + threadIdx.x;
  if (e >= ETOT) return;
  int d = (e < ERAW) ? edst[e] : (e - ERAW);
  atomicAdd(&deg[d], 1);
}

__global__ __launch_bounds__(256) void scan_deg(
    const int* __restrict__ deg, int* __restrict__ rowptr) {
  __shared__ int part[256];
  const int t = threadIdx.x;
  const int CHUNK = (NN + 255) / 256;
  int lo = t * CHUNK, hi = min(lo + CHUNK, NN);
  int s = 0;
  for (int i = lo; i < hi; ++i) s += deg[i];
  part[t] = s;
  __syncthreads();
  for (int off = 1; off < 256; off <<= 1) {
    int v = (t >= off) ? part[t - off] : 0;
    __syncthreads();
    part[t] += v;
    __syncthreads();
  }
  int base = (t == 0) ? 0 : part[t - 1];
  for (int i = lo; i < hi; ++i) {
    rowptr[i] = base;
    base += deg[i];
  }
  if (t == 255) rowptr[NN] = part[255];
}

__global__ __launch_bounds__(256) void scatter_csr(
    const int* __restrict__ esrc, const int* __restrict__ edst,
    const int* __restrict__ rowptr, int* __restrict__ cnt,
    int* __restrict__ csrc) {
  int e = blockIdx.x * blockDim.x + threadIdx.x;
  if (e >= ETOT) return;
  int s, d;
  if (e < ERAW) { s = esrc[e]; d = edst[e]; }
  else          { s = e - ERAW; d = e - ERAW; }
  int pos = rowptr[d] + atomicAdd(&cnt[d], 1);
  csrc[pos] = s;
}

// ---- CSR-order edge softmax: alpha[p*H+h] = normalized attention ----------
template <int H>
__global__ __launch_bounds__(256) void csr_softmax(
    const int* __restrict__ rowptr, const int* __restrict__ csrc,
    const float* __restrict__ al_s, const float* __restrict__ al_d,
    float* __restrict__ alpha) {
  const int w = threadIdx.x >> 6, lane = threadIdx.x & 63;
  const int d = blockIdx.x * 4 + w;
  if (d >= NN) return;
  const int r0 = rowptr[d], r1 = rowptr[d + 1];
  float ald[H];
  #pragma unroll
  for (int h = 0; h < H; ++h) ald[h] = al_d[d * H + h];

  float mx[H];
  #pragma unroll
  for (int h = 0; h < H; ++h) mx[h] = -3.4e38f;
  for (int p = r0 + lane; p < r1; p += 64) {
    int s = csrc[p];
    #pragma unroll
    for (int h = 0; h < H; ++h) {
      float v = al_s[s * H + h] + ald[h];
      v = (v > 0.f) ? v : 0.2f * v;
      mx[h] = fmaxf(mx[h], v);
    }
  }
  #pragma unroll
  for (int o = 32; o; o >>= 1)
    #pragma unroll
    for (int h = 0; h < H; ++h) mx[h] = fmaxf(mx[h], __shfl_xor(mx[h], o));

  float zs[H];
  #pragma unroll
  for (int h = 0; h < H; ++h) zs[h] = 0.f;
  for (int p = r0 + lane; p < r1; p += 64) {
    int s = csrc[p];
    #pragma unroll
    for (int h = 0; h < H; ++h) {
      float v = al_s[s * H + h] + ald[h];
      v = (v > 0.f) ? v : 0.2f * v;
      float e = __expf(v - mx[h]);
      alpha[(size_t)p * H + h] = e;
      zs[h] += e;
    }
  }
  #pragma unroll
  for (int o = 32; o; o >>= 1)
    #pragma unroll
    for (int h = 0; h < H; ++h) zs[h] += __shfl_xor(zs[h], o);
  float iz[H];
  #pragma unroll
  for (int h = 0; h < H; ++h) iz[h] = 1.0f / (zs[h] + 1e-16f);

  for (int p = r0 + lane; p < r1; p += 64) {
    #pragma unroll
    for (int h = 0; h < H; ++h) alpha[(size_t)p * H + h] *= iz[h];
  }
}

// ---- layer-1: aggregate raw x per head into PADDED [NN, 512] layout -------
// aggx[d, h*64+k] = sum_e alpha[e,h] * x[src_e, k]  (k<50; zeros for k>=50)
__global__ __launch_bounds__(256) void agg_x(
    const int* __restrict__ rowptr, const int* __restrict__ csrc,
    const float* __restrict__ alpha, const float* __restrict__ x,
    float* __restrict__ aggx) {
  const int w = threadIdx.x >> 6, lane = threadIdx.x & 63;
  const int d = blockIdx.x * 4 + w;
  if (d >= NN) return;
  const int r0 = rowptr[d], r1 = rowptr[d + 1];
  float acc[HEADS];
  #pragma unroll
  for (int h = 0; h < HEADS; ++h) acc[h] = 0.f;
  for (int p = r0; p < r1; ++p) {
    int s = csrc[p];
    float av = alpha[(size_t)p * HEADS + (lane & 7)];
    float xv = (lane < F_IN) ? x[(size_t)s * F_IN + lane] : 0.f;
    #pragma unroll
    for (int h = 0; h < HEADS; ++h) acc[h] += __shfl(av, h, 8) * xv;
  }
  #pragma unroll
  for (int h = 0; h < HEADS; ++h)
    aggx[(size_t)d * WIDTH + h * HID + lane] = (lane < F_IN) ? acc[h] : 0.f;
}

// ---- pull aggregation (H=1): alpha pre-normalized, CSR order --------------
template <int M, bool ELU>
__global__ __launch_bounds__(256) void pull_agg(
    const int* __restrict__ rowptr, const int* __restrict__ csrc,
    const float* __restrict__ alpha, const float* __restrict__ h,
    const float* __restrict__ bias, float* __restrict__ out) {
  constexpr int EPL = (M + 63) / 64;
  const int w = threadIdx.x >> 6;
  const int lane = threadIdx.x & 63;
  const int d = blockIdx.x * 4 + w;
  if (d >= NN) return;
  const int r0 = rowptr[d], r1 = rowptr[d + 1];
  const int base = lane * EPL;

  float acc[EPL];
  #pragma unroll
  for (int j = 0; j < EPL; ++j) acc[j] = 0.f;
  for (int p = r0; p < r1; ++p) {
    int s = csrc[p];
    float a = alpha[p];
    const float* hr = h + (size_t)s * M + base;
    #pragma unroll
    for (int j = 0; j < EPL; ++j) {
      if ((M % 64 == 0) || (base + j < M)) acc[j] += hr[j] * a;
    }
  }

  float* od = out + (size_t)d * M + base;
  #pragma unroll
  for (int j = 0; j < EPL; ++j) {
    if ((M % 64 == 0) || (base + j < M)) {
      float v = acc[j] + bias[base + j];
      if (ELU) v = (v > 0.f) ? v : (__expf(v) - 1.0f);
      od[j] = v;
    }
  }
}

extern "C" void kernel_launch(void* const* d_in, const int* in_sizes, int n_in,
                              void* d_out, int out_size, void* d_ws,
                              size_t ws_size, hipStream_t stream) {
  const float* x      = (const float*)d_in[0];
  const int*   ei     = (const int*)d_in[1];
  const float* W1     = (const float*)d_in[2];
  const float* a1_src = (const float*)d_in[3];
  const float* a1_dst = (const float*)d_in[4];
  const float* b1     = (const float*)d_in[5];
  const float* W2     = (const float*)d_in[6];
  const float* a2_src = (const float*)d_in[7];
  const float* a2_dst = (const float*)d_in[8];
  const float* b2     = (const float*)d_in[9];
  const float* W3     = (const float*)d_in[10];
  const float* a3_src = (const float*)d_in[11];
  const float* a3_dst = (const float*)d_in[12];
  const float* b3     = (const float*)d_in[13];
  float* out = (float*)d_out;

  const int* esrc = ei;
  const int* edst = ei + ERAW;

  // Workspace carve-up
  unsigned short* aHi  = (unsigned short*)d_ws;           // NN*WIDTH
  unsigned short* aLo  = aHi + (size_t)NN * WIDTH;
  unsigned short* w1tHi = aLo + (size_t)NN * WIDTH;       // 512*512 blockdiag
  unsigned short* w1tLo = w1tHi + (size_t)WIDTH * WIDTH;
  unsigned short* w2tHi = w1tLo + (size_t)WIDTH * WIDTH;  // 512*512
  unsigned short* w2tLo = w2tHi + (size_t)WIDTH * WIDTH;
  unsigned short* w3tHi = w2tLo + (size_t)WIDTH * WIDTH;  // 128*512
  unsigned short* w3tLo = w3tHi + (size_t)NCLS_P * WIDTH;
  float* bufA   = (float*)(w3tLo + (size_t)NCLS_P * WIDTH);  // NN*WIDTH
  float* bufB   = bufA + (size_t)NN * WIDTH;
  float* alpha  = bufB + (size_t)NN * WIDTH;              // ETOT*HEADS
  float* al_s   = alpha + (size_t)ETOT * HEADS;
  float* al_d   = al_s + (size_t)NN * HEADS;
  float* w1as   = al_d + (size_t)NN * HEADS;              // 50*8
  float* w1ad   = w1as + F_IN * HEADS;
  int* deg      = (int*)(w1ad + F_IN * HEADS);
  int* rowptr   = deg + NN;
  int* cnt      = rowptr + NN + 4;
  int* csrc     = cnt + NN;                               // ETOT
  float* aggx   = bufA;  // alias: bufA free during layer 1

  // ---- build CSR by destination (once) ----
  hipMemsetAsync(deg, 0, (size_t)NN * sizeof(int), stream);
  hipMemsetAsync(cnt, 0, (size_t)NN * sizeof(int), stream);
  const int eblk = (ETOT + 255) / 256;
  count_deg<<<eblk, 256, 0, stream>>>(edst, deg);
  scan_deg<<<1, 256, 0, stream>>>(deg, rowptr);
  scatter_csr<<<eblk, 256, 0, stream>>>(esrc, edst, rowptr, cnt, csrc);

  // ---- weight prep (once) ----
  build_w1bd_t<<<(WIDTH * WIDTH + 255) / 256, 256, 0, stream>>>(W1, w1tHi,
                                                                w1tLo);
  transpose_split<<<dim3(WIDTH / 32, WIDTH / 32), 256, 0, stream>>>(
      W2, w2tHi, w2tLo, WIDTH, WIDTH, WIDTH);
  transpose_split<<<dim3(WIDTH / 32, NCLS_P / 32), 256, 0, stream>>>(
      W3, w3tHi, w3tLo, WIDTH, NCLS, NCLS_P);

  const int nwblk = (NN + 3) / 4;
  const int splitblk = ((NN * WIDTH / 4) + 255) / 256;

  // ---- Layer 1 (aggregate-x-first, padded blockdiag MFMA GEMM) ----
  {
    fold_w1a<<<(2 * F_IN * HEADS + 255) / 256, 256, 0, stream>>>(
        W1, a1_src, a1_dst, w1as, w1ad);
    al1_kernel<<<nwblk, 256, 0, stream>>>(x, w1as, w1ad, al_s, al_d);
    csr_softmax<HEADS><<<nwblk, 256, 0, stream>>>(rowptr, csrc, al_s, al_d,
                                                  alpha);
    agg_x<<<nwblk, 256, 0, stream>>>(rowptr, csrc, alpha, x, aggx);
    split_hi_lo4<<<splitblk, 256, 0, stream>>>((const float4*)aggx,
                                               (ushort4*)aHi, (ushort4*)aLo,
                                               NN * WIDTH / 4);
    gemm_mfma_split<true><<<dim3(WIDTH / 128, (NN + 127) / 128), 256, 0,
                            stream>>>(aHi, aLo, w1tHi, w1tLo, bufB, b1, NN,
                                      WIDTH, WIDTH);
  }
  // ---- Layer 2: bufB @ W2 -> h2(bufA) via split-bf16 MFMA ----
  {
    split_hi_lo4<<<splitblk, 256, 0, stream>>>((const float4*)bufB,
                                               (ushort4*)aHi, (ushort4*)aLo,
                                               NN * WIDTH / 4);
    gemm_mfma_split<false><<<dim3(WIDTH / 128, (NN + 127) / 128), 256, 0,
                             stream>>>(aHi, aLo, w2tHi, w2tLo, bufA, nullptr,
                                       NN, WIDTH, WIDTH);
    compute_al<<<nwblk, 256, 0, stream>>>(bufA, a2_src, a2_dst, al_s, al_d,
                                          NN, 1, WIDTH);
    csr_softmax<1><<<nwblk, 256, 0, stream>>>(rowptr, csrc, al_s, al_d,
                                              alpha);
    pull_agg<WIDTH, true><<<nwblk, 256, 0, stream>>>(rowptr, csrc, alpha,
                                                     bufA, b2, bufB);
  }
  // ---- Layer 3: bufB @ W3 -> h3(bufA); agg -> out (no ELU) ----
  {
    split_hi_lo4<<<splitblk, 256, 0, stream>>>((const float4*)bufB,
                                               (ushort4*)aHi, (ushort4*)aLo,
                                               NN * WIDTH / 4);
    gemm_mfma_split<false><<<dim3(NCLS_P / 128, (NN + 127) / 128), 256, 0,
                             stream>>>(aHi, aLo, w3tHi, w3tLo, bufA, nullptr,
                                       NN, WIDTH, NCLS);
    compute_al<<<nwblk, 256, 0, stream>>>(bufA, a3_src, a3_dst, al_s, al_d,
                                          NN, 1, NCLS);
    csr_softmax<1><<<nwblk, 256, 0, stream>>>(rowptr, csrc, al_s, al_d,
                                              alpha);
    pull_agg<NCLS, false><<<nwblk, 256, 0, stream>>>(rowptr, csrc, alpha,
                                                     bufA, b3, out);
  }
}

// Round 7
// 601.876 us; speedup vs baseline: 1.4920x; 1.0562x over previous
//
#include <hip/hip_runtime.h>
#include <hip/hip_bf16.h>

// Problem constants (match reference)
#define NN     20000
#define ERAW   320000
#define ETOT   (ERAW + NN)   // 340000 with self loops
#define F_IN   50
#define HID    64
#define HEADS  8
#define WIDTH  512           // HID*HEADS
#define NCLS   121
#define NCLS_P 128           // padded cols for layer-3 MFMA GEMM

typedef __attribute__((ext_vector_type(8))) __bf16 bf16x8;
typedef __attribute__((ext_vector_type(4))) float floatx4;

// ---------------- fp32 -> bf16 split helpers --------------------------------
__device__ __forceinline__ unsigned short f32_to_bf16_rn(float f) {
  unsigned u = __float_as_uint(f);
  unsigned r = u + 0x7fffu + ((u >> 16) & 1u);
  return (unsigned short)(r >> 16);
}
__device__ __forceinline__ void split_one(float f, unsigned short& h,
                                          unsigned short& l) {
  h = f32_to_bf16_rn(f);
  float fh = __uint_as_float(((unsigned)h) << 16);
  l = f32_to_bf16_rn(f - fh);
}

// W [K][M] fp32 -> Bt hi/lo [Mp][K] bf16 ushort (rows m>=M zero-padded)
__global__ __launch_bounds__(256) void transpose_split(
    const float* __restrict__ W, unsigned short* __restrict__ thi,
    unsigned short* __restrict__ tlo, int K, int M, int Mp) {
  __shared__ float t[32][33];
  int k0 = blockIdx.x * 32, m0 = blockIdx.y * 32;
  int tx = threadIdx.x & 31, ty = threadIdx.x >> 5;  // 32 x 8
  #pragma unroll
  for (int r = 0; r < 4; ++r) {
    int k = k0 + ty + r * 8, m = m0 + tx;
    float v = 0.f;
    if (k < K && m < M) v = W[(size_t)k * M + m];
    t[ty + r * 8][tx] = v;
  }
  __syncthreads();
  #pragma unroll
  for (int r = 0; r < 4; ++r) {
    int m = m0 + ty + r * 8, k = k0 + tx;
    if (m < Mp && k < K) {
      unsigned short h, l;
      split_one(t[tx][ty + r * 8], h, l);
      thi[(size_t)m * K + k] = h;
      tlo[(size_t)m * K + k] = l;
    }
  }
}

// Build block-diagonal W1 Bt[512][512]: Bt[m][kk] = W1[kk&63][m] iff
// kk>>6 == m>>6 and (kk&63) < 50, else 0.
__global__ __launch_bounds__(256) void build_w1bd_t(
    const float* __restrict__ W1, unsigned short* __restrict__ thi,
    unsigned short* __restrict__ tlo) {
  int idx = blockIdx.x * blockDim.x + threadIdx.x;
  if (idx >= WIDTH * WIDTH) return;
  int m = idx >> 9, kk = idx & 511;
  float v = 0.f;
  if ((kk >> 6) == (m >> 6) && (kk & 63) < F_IN)
    v = W1[(size_t)(kk & 63) * WIDTH + m];
  unsigned short h, l;
  split_one(v, h, l);
  thi[idx] = h;
  tlo[idx] = l;
}

// ---- split-bf16 MFMA GEMM: C[N,M] = A[N,K] @ B[K,M] (B given as Bt[Mp][K]) -
// MODE 0: write fp32 C.
// MODE 1: v = elu(acc + bias[col]); write bf16-split (outHi/outLo). (layer 1)
template <int MODE>
__global__ __launch_bounds__(256) void gemm_mfma_split(
    const unsigned short* __restrict__ Ahi, const unsigned short* __restrict__ Alo,
    const unsigned short* __restrict__ Bthi, const unsigned short* __restrict__ Btlo,
    float* __restrict__ C, unsigned short* __restrict__ outHi,
    unsigned short* __restrict__ outLo, const float* __restrict__ bias,
    int N, int K, int M) {
  __shared__ unsigned short sAhi[4096], sAlo[4096], sBhi[4096], sBlo[4096];
  const int tid = threadIdx.x;
  const int wave = tid >> 6, lane = tid & 63;
  const int wr = wave >> 1, wc = wave & 1;
  const int r0 = blockIdx.y * 128;
  const int c0 = blockIdx.x * 128;
  const int lkg = lane >> 4;
  const int lmn = lane & 15;

  const int skg = tid & 3;
  const int srow = tid >> 2;
  int ra0 = r0 + srow;        if (ra0 > NN - 1) ra0 = NN - 1;
  int ra1 = r0 + srow + 64;   if (ra1 > NN - 1) ra1 = NN - 1;
  const unsigned short* gAhi0 = Ahi + (size_t)ra0 * K + skg * 8;
  const unsigned short* gAhi1 = Ahi + (size_t)ra1 * K + skg * 8;
  const unsigned short* gAlo0 = Alo + (size_t)ra0 * K + skg * 8;
  const unsigned short* gAlo1 = Alo + (size_t)ra1 * K + skg * 8;
  const unsigned short* gBhi0 = Bthi + (size_t)(c0 + srow) * K + skg * 8;
  const unsigned short* gBhi1 = Bthi + (size_t)(c0 + srow + 64) * K + skg * 8;
  const unsigned short* gBlo0 = Btlo + (size_t)(c0 + srow) * K + skg * 8;
  const unsigned short* gBlo1 = Btlo + (size_t)(c0 + srow + 64) * K + skg * 8;

  floatx4 acc[4][4] = {};

  uint4 a0, a1, a2, a3, b0, b1, b2, b3;
  auto gload = [&](int kk) {
    a0 = *(const uint4*)(gAhi0 + kk);
    a1 = *(const uint4*)(gAhi1 + kk);
    a2 = *(const uint4*)(gAlo0 + kk);
    a3 = *(const uint4*)(gAlo1 + kk);
    b0 = *(const uint4*)(gBhi0 + kk);
    b1 = *(const uint4*)(gBhi1 + kk);
    b2 = *(const uint4*)(gBlo0 + kk);
    b3 = *(const uint4*)(gBlo1 + kk);
  };
  gload(0);

  const int w0 = (skg * 128 + srow) * 8;
  const int w1 = (skg * 128 + srow + 64) * 8;

  for (int k0 = 0; k0 < K; k0 += 32) {
    __syncthreads();
    *(uint4*)(sAhi + w0) = a0;
    *(uint4*)(sAhi + w1) = a1;
    *(uint4*)(sAlo + w0) = a2;
    *(uint4*)(sAlo + w1) = a3;
    *(uint4*)(sBhi + w0) = b0;
    *(uint4*)(sBhi + w1) = b1;
    *(uint4*)(sBlo + w0) = b2;
    *(uint4*)(sBlo + w1) = b3;
    __syncthreads();
    if (k0 + 32 < K) gload(k0 + 32);

    bf16x8 fAhi[4], fAlo[4], fBhi[4], fBlo[4];
    #pragma unroll
    for (int mi = 0; mi < 4; ++mi) {
      int m = wr * 64 + mi * 16 + lmn;
      fAhi[mi] = *(const bf16x8*)(sAhi + (lkg * 128 + m) * 8);
      fAlo[mi] = *(const bf16x8*)(sAlo + (lkg * 128 + m) * 8);
    }
    #pragma unroll
    for (int ni = 0; ni < 4; ++ni) {
      int n = wc * 64 + ni * 16 + lmn;
      fBhi[ni] = *(const bf16x8*)(sBhi + (lkg * 128 + n) * 8);
      fBlo[ni] = *(const bf16x8*)(sBlo + (lkg * 128 + n) * 8);
    }
    #pragma unroll
    for (int mi = 0; mi < 4; ++mi)
      #pragma unroll
      for (int ni = 0; ni < 4; ++ni) {
        acc[mi][ni] = __builtin_amdgcn_mfma_f32_16x16x32_bf16(
            fAhi[mi], fBhi[ni], acc[mi][ni], 0, 0, 0);
        acc[mi][ni] = __builtin_amdgcn_mfma_f32_16x16x32_bf16(
            fAhi[mi], fBlo[ni], acc[mi][ni], 0, 0, 0);
        acc[mi][ni] = __builtin_amdgcn_mfma_f32_16x16x32_bf16(
            fAlo[mi], fBhi[ni], acc[mi][ni], 0, 0, 0);
      }
  }

  #pragma unroll
  for (int mi = 0; mi < 4; ++mi) {
    #pragma unroll
    for (int r = 0; r < 4; ++r) {
      int grow = r0 + wr * 64 + mi * 16 + (lane >> 4) * 4 + r;
      if (grow >= N) continue;
      #pragma unroll
      for (int ni = 0; ni < 4; ++ni) {
        int gcol = c0 + wc * 64 + ni * 16 + lmn;
        if (gcol < M) {
          float v = acc[mi][ni][r];
          if (MODE == 1) {
            v += bias[gcol];
            v = (v > 0.f) ? v : (__expf(v) - 1.0f);
            unsigned short hh, ll;
            split_one(v, hh, ll);
            outHi[(size_t)grow * M + gcol] = hh;
            outLo[(size_t)grow * M + gcol] = ll;
          } else {
            C[(size_t)grow * M + gcol] = v;
          }
        }
      }
    }
  }
}

// ---------------- layer-1 folded attention weights --------------------------
__global__ __launch_bounds__(256) void fold_w1a(
    const float* __restrict__ W1, const float* __restrict__ a1s,
    const float* __restrict__ a1d, float* __restrict__ w1as,
    float* __restrict__ w1ad) {
  int idx = blockIdx.x * blockDim.x + threadIdx.x;
  if (idx >= 2 * F_IN * HEADS) return;
  int which = idx >= F_IN * HEADS;
  int r = which ? idx - F_IN * HEADS : idx;
  int k = r >> 3, h = r & 7;
  const float* a = which ? a1d : a1s;
  float s = 0.f;
  for (int c = 0; c < HID; ++c) s += W1[(size_t)k * WIDTH + h * HID + c] * a[h * HID + c];
  (which ? w1ad : w1as)[r] = s;
}

// al1[n,h] = sum_k x[n,k] * w1a[k,h]   (one wave per node)
__global__ __launch_bounds__(256) void al1_kernel(
    const float* __restrict__ x, const float* __restrict__ w1as,
    const float* __restrict__ w1ad, float* __restrict__ al_s,
    float* __restrict__ al_d) {
  int n = (blockIdx.x * blockDim.x + threadIdx.x) >> 6;
  int lane = threadIdx.x & 63;
  if (n >= NN) return;
  float xv = (lane < F_IN) ? x[(size_t)n * F_IN + lane] : 0.f;
  float ws[HEADS], wd[HEADS];
  #pragma unroll
  for (int h = 0; h < HEADS; ++h) {
    ws[h] = (lane < F_IN) ? w1as[lane * HEADS + h] : 0.f;
    wd[h] = (lane < F_IN) ? w1ad[lane * HEADS + h] : 0.f;
  }
  #pragma unroll
  for (int h = 0; h < HEADS; ++h) {
    float ss = xv * ws[h], sd = xv * wd[h];
    #pragma unroll
    for (int o = 32; o; o >>= 1) {
      ss += __shfl_xor(ss, o);
      sd += __shfl_xor(sd, o);
    }
    if (lane == 0) {
      al_s[n * HEADS + h] = ss;
      al_d[n * HEADS + h] = sd;
    }
  }
}

// ---------------- per-node attention logits (from h; H=1 layers) -----------
__global__ __launch_bounds__(256) void compute_al(
    const float* __restrict__ h, const float* __restrict__ a_src,
    const float* __restrict__ a_dst, float* __restrict__ al_s,
    float* __restrict__ al_d, int Nn, int H, int C) {
  int wave = (blockIdx.x * blockDim.x + threadIdx.x) >> 6;
  int lane = threadIdx.x & 63;
  if (wave >= Nn) return;
  const float* hr = h + (size_t)wave * H * C;
  for (int hd = 0; hd < H; ++hd) {
    float ss = 0.f, sd = 0.f;
    for (int c = lane; c < C; c += 64) {
      float v = hr[hd * C + c];
      ss += v * a_src[hd * C + c];
      sd += v * a_dst[hd * C + c];
    }
    #pragma unroll
    for (int o = 32; o; o >>= 1) {
      ss += __shfl_xor(ss, o);
      sd += __shfl_xor(sd, o);
    }
    if (lane == 0) {
      al_s[wave * H + hd] = ss;
      al_d[wave * H + hd] = sd;
    }
  }
}

// ---------------- CSR build (once; shared by all layers) --------------------
__global__ __launch_bounds__(256) void count_deg(
    const int* __restrict__ edst, int* __restrict__ deg) {
  int e = blockIdx.x * blockDim.x + threadIdx.x;
  if (e >= ETOT) return;
  int d = (e < ERAW) ? edst[e] : (e - ERAW);
  atomicAdd(&deg[d], 1);
}

__global__ __launch_bounds__(256) void scan_deg(
    const int* __restrict__ deg, int* __restrict__ rowptr) {
  __shared__ int part[256];
  const int t = threadIdx.x;
  const int CHUNK = (NN + 255) / 256;
  int lo = t * CHUNK, hi = min(lo + CHUNK, NN);
  int s = 0;
  for (int i = lo; i < hi; ++i) s += deg[i];
  part[t] = s;
  __syncthreads();
  for (int off = 1; off < 256; off <<= 1) {
    int v = (t >= off) ? part[t - off] : 0;
    __syncthreads();
    part[t] += v;
    __syncthreads();
  }
  int base = (t == 0) ? 0 : part[t - 1];
  for (int i = lo; i < hi; ++i) {
    rowptr[i] = base;
    base += deg[i];
  }
  if (t == 255) rowptr[NN] = part[255];
}

__global__ __launch_bounds__(256) void scatter_csr(
    const int* __restrict__ esrc, const int* __restrict__ edst,
    const int* __restrict__ rowptr, int* __restrict__ cnt,
    int* __restrict__ csrc) {
  int e = blockIdx.x * blockDim.x + threadIdx.x;
  if (e >= ETOT) return;
  int s, d;
  if (e < ERAW) { s = esrc[e]; d = edst[e]; }
  else          { s = e - ERAW; d = e - ERAW; }
  int pos = rowptr[d] + atomicAdd(&cnt[d], 1);
  csrc[pos] = s;
}

// ---- CSR-order edge softmax: alpha[p*H+h] = normalized attention ----------
template <int H>
__global__ __launch_bounds__(256) void csr_softmax(
    const int* __restrict__ rowptr, const int* __restrict__ csrc,
    const float* __restrict__ al_s, const float* __restrict__ al_d,
    float* __restrict__ alpha) {
  const int w = threadIdx.x >> 6, lane = threadIdx.x & 63;
  const int d = blockIdx.x * 4 + w;
  if (d >= NN) return;
  const int r0 = rowptr[d], r1 = rowptr[d + 1];
  float ald[H];
  #pragma unroll
  for (int h = 0; h < H; ++h) ald[h] = al_d[d * H + h];

  float mx[H];
  #pragma unroll
  for (int h = 0; h < H; ++h) mx[h] = -3.4e38f;
  for (int p = r0 + lane; p < r1; p += 64) {
    int s = csrc[p];
    #pragma unroll
    for (int h = 0; h < H; ++h) {
      float v = al_s[s * H + h] + ald[h];
      v = (v > 0.f) ? v : 0.2f * v;
      mx[h] = fmaxf(mx[h], v);
    }
  }
  #pragma unroll
  for (int o = 32; o; o >>= 1)
    #pragma unroll
    for (int h = 0; h < H; ++h) mx[h] = fmaxf(mx[h], __shfl_xor(mx[h], o));

  float zs[H];
  #pragma unroll
  for (int h = 0; h < H; ++h) zs[h] = 0.f;
  for (int p = r0 + lane; p < r1; p += 64) {
    int s = csrc[p];
    #pragma unroll
    for (int h = 0; h < H; ++h) {
      float v = al_s[s * H + h] + ald[h];
      v = (v > 0.f) ? v : 0.2f * v;
      float e = __expf(v - mx[h]);
      alpha[(size_t)p * H + h] = e;
      zs[h] += e;
    }
  }
  #pragma unroll
  for (int o = 32; o; o >>= 1)
    #pragma unroll
    for (int h = 0; h < H; ++h) zs[h] += __shfl_xor(zs[h], o);
  float iz[H];
  #pragma unroll
  for (int h = 0; h < H; ++h) iz[h] = 1.0f / (zs[h] + 1e-16f);

  for (int p = r0 + lane; p < r1; p += 64) {
    #pragma unroll
    for (int h = 0; h < H; ++h) alpha[(size_t)p * H + h] *= iz[h];
  }
}

// ---- layer-1: aggregate raw x per head; write bf16-split PADDED [NN,512] --
// cols h*64+k: k<50 = sum_e alpha[e,h]*x[src_e,k]; k>=50 zero.
__global__ __launch_bounds__(256) void agg_x(
    const int* __restrict__ rowptr, const int* __restrict__ csrc,
    const float* __restrict__ alpha, const float* __restrict__ x,
    unsigned short* __restrict__ outHi, unsigned short* __restrict__ outLo) {
  const int w = threadIdx.x >> 6, lane = threadIdx.x & 63;
  const int d = blockIdx.x * 4 + w;
  if (d >= NN) return;
  const int r0 = rowptr[d], r1 = rowptr[d + 1];
  float acc[HEADS];
  #pragma unroll
  for (int h = 0; h < HEADS; ++h) acc[h] = 0.f;
  for (int p = r0; p < r1; ++p) {
    int s = csrc[p];
    float av = alpha[(size_t)p * HEADS + (lane & 7)];
    float xv = (lane < F_IN) ? x[(size_t)s * F_IN + lane] : 0.f;
    #pragma unroll
    for (int h = 0; h < HEADS; ++h) acc[h] += __shfl(av, h, 8) * xv;
  }
  #pragma unroll
  for (int h = 0; h < HEADS; ++h) {
    float v = (lane < F_IN) ? acc[h] : 0.f;
    unsigned short hh, ll;
    split_one(v, hh, ll);
    outHi[(size_t)d * WIDTH + h * HID + lane] = hh;
    outLo[(size_t)d * WIDTH + h * HID + lane] = ll;
  }
}

// ---- pull aggregation (H=1): alpha pre-normalized, CSR order --------------
// SPLIT: write bf16 hi/lo instead of fp32 (feeds next layer's MFMA GEMM).
template <int M, bool ELU, bool SPLIT>
__global__ __launch_bounds__(256) void pull_agg(
    const int* __restrict__ rowptr, const int* __restrict__ csrc,
    const float* __restrict__ alpha, const float* __restrict__ h,
    const float* __restrict__ bias, float* __restrict__ out,
    unsigned short* __restrict__ outHi, unsigned short* __restrict__ outLo) {
  constexpr int EPL = (M + 63) / 64;
  const int w = threadIdx.x >> 6;
  const int lane = threadIdx.x & 63;
  const int d = blockIdx.x * 4 + w;
  if (d >= NN) return;
  const int r0 = rowptr[d], r1 = rowptr[d + 1];
  const int base = lane * EPL;

  float acc[EPL];
  #pragma unroll
  for (int j = 0; j < EPL; ++j) acc[j] = 0.f;
  for (int p = r0; p < r1; ++p) {
    int s = csrc[p];
    float a = alpha[p];
    const float* hr = h + (size_t)s * M + base;
    #pragma unroll
    for (int j = 0; j < EPL; ++j) {
      if ((M % 64 == 0) || (base + j < M)) acc[j] += hr[j] * a;
    }
  }

  #pragma unroll
  for (int j = 0; j < EPL; ++j) {
    if ((M % 64 == 0) || (base + j < M)) {
      float v = acc[j] + bias[base + j];
      if (ELU) v = (v > 0.f) ? v : (__expf(v) - 1.0f);
      if (SPLIT) {
        unsigned short hh, ll;
        split_one(v, hh, ll);
        outHi[(size_t)d * M + base + j] = hh;
        outLo[(size_t)d * M + base + j] = ll;
      } else {
        out[(size_t)d * M + base + j] = v;
      }
    }
  }
}

extern "C" void kernel_launch(void* const* d_in, const int* in_sizes, int n_in,
                              void* d_out, int out_size, void* d_ws,
                              size_t ws_size, hipStream_t stream) {
  const float* x      = (const float*)d_in[0];
  const int*   ei     = (const int*)d_in[1];
  const float* W1     = (const float*)d_in[2];
  const float* a1_src = (const float*)d_in[3];
  const float* a1_dst = (const float*)d_in[4];
  const float* b1     = (const float*)d_in[5];
  const float* W2     = (const float*)d_in[6];
  const float* a2_src = (const float*)d_in[7];
  const float* a2_dst = (const float*)d_in[8];
  const float* b2     = (const float*)d_in[9];
  const float* W3     = (const float*)d_in[10];
  const float* a3_src = (const float*)d_in[11];
  const float* a3_dst = (const float*)d_in[12];
  const float* b3     = (const float*)d_in[13];
  float* out = (float*)d_out;

  const int* esrc = ei;
  const int* edst = ei + ERAW;

  // Workspace carve-up
  // Ping-pong bf16-split activation pairs:
  //   P1: agg_x out (L1 gemm A) -> free -> L2 pull_agg out (L3 gemm A)
  //   P2: L1 gemm out (L2 gemm A)
  unsigned short* p1Hi  = (unsigned short*)d_ws;          // NN*WIDTH
  unsigned short* p1Lo  = p1Hi + (size_t)NN * WIDTH;
  unsigned short* p2Hi  = p1Lo + (size_t)NN * WIDTH;
  unsigned short* p2Lo  = p2Hi + (size_t)NN * WIDTH;
  unsigned short* w1tHi = p2Lo + (size_t)NN * WIDTH;      // 512*512 blockdiag
  unsigned short* w1tLo = w1tHi + (size_t)WIDTH * WIDTH;
  unsigned short* w2tHi = w1tLo + (size_t)WIDTH * WIDTH;  // 512*512
  unsigned short* w2tLo = w2tHi + (size_t)WIDTH * WIDTH;
  unsigned short* w3tHi = w2tLo + (size_t)WIDTH * WIDTH;  // 128*512
  unsigned short* w3tLo = w3tHi + (size_t)NCLS_P * WIDTH;
  float* bufA   = (float*)(w3tLo + (size_t)NCLS_P * WIDTH);  // NN*WIDTH (h)
  float* alpha  = bufA + (size_t)NN * WIDTH;              // ETOT*HEADS
  float* al_s   = alpha + (size_t)ETOT * HEADS;
  float* al_d   = al_s + (size_t)NN * HEADS;
  float* w1as   = al_d + (size_t)NN * HEADS;              // 50*8
  float* w1ad   = w1as + F_IN * HEADS;
  int* deg      = (int*)(w1ad + F_IN * HEADS);
  int* rowptr   = deg + NN;
  int* cnt      = rowptr + NN + 4;
  int* csrc     = cnt + NN;                               // ETOT

  // ---- build CSR by destination (once) ----
  hipMemsetAsync(deg, 0, (size_t)NN * sizeof(int), stream);
  hipMemsetAsync(cnt, 0, (size_t)NN * sizeof(int), stream);
  const int eblk = (ETOT + 255) / 256;
  count_deg<<<eblk, 256, 0, stream>>>(edst, deg);
  scan_deg<<<1, 256, 0, stream>>>(deg, rowptr);
  scatter_csr<<<eblk, 256, 0, stream>>>(esrc, edst, rowptr, cnt, csrc);

  // ---- weight prep (once) ----
  build_w1bd_t<<<(WIDTH * WIDTH + 255) / 256, 256, 0, stream>>>(W1, w1tHi,
                                                                w1tLo);
  transpose_split<<<dim3(WIDTH / 32, WIDTH / 32), 256, 0, stream>>>(
      W2, w2tHi, w2tLo, WIDTH, WIDTH, WIDTH);
  transpose_split<<<dim3(WIDTH / 32, NCLS_P / 32), 256, 0, stream>>>(
      W3, w3tHi, w3tLo, WIDTH, NCLS, NCLS_P);

  const int nwblk = (NN + 3) / 4;

  // ---- Layer 1 (aggregate-x-first; all-bf16-split dataflow) ----
  {
    fold_w1a<<<(2 * F_IN * HEADS + 255) / 256, 256, 0, stream>>>(
        W1, a1_src, a1_dst, w1as, w1ad);
    al1_kernel<<<nwblk, 256, 0, stream>>>(x, w1as, w1ad, al_s, al_d);
    csr_softmax<HEADS><<<nwblk, 256, 0, stream>>>(rowptr, csrc, al_s, al_d,
                                                  alpha);
    agg_x<<<nwblk, 256, 0, stream>>>(rowptr, csrc, alpha, x, p1Hi, p1Lo);
    // x1 = elu(aggx @ W1bd + b1), written directly as bf16 split -> P2
    gemm_mfma_split<1><<<dim3(WIDTH / 128, (NN + 127) / 128), 256, 0,
                         stream>>>(p1Hi, p1Lo, w1tHi, w1tLo, nullptr, p2Hi,
                                   p2Lo, b1, NN, WIDTH, WIDTH);
  }
  // ---- Layer 2: h2 = x1 @ W2 (fp32 out for al/gather); agg -> P1 split ----
  {
    gemm_mfma_split<0><<<dim3(WIDTH / 128, (NN + 127) / 128), 256, 0,
                         stream>>>(p2Hi, p2Lo, w2tHi, w2tLo, bufA, nullptr,
                                   nullptr, nullptr, NN, WIDTH, WIDTH);
    compute_al<<<nwblk, 256, 0, stream>>>(bufA, a2_src, a2_dst, al_s, al_d,
                                          NN, 1, WIDTH);
    csr_softmax<1><<<nwblk, 256, 0, stream>>>(rowptr, csrc, al_s, al_d,
                                              alpha);
    pull_agg<WIDTH, true, true><<<nwblk, 256, 0, stream>>>(
        rowptr, csrc, alpha, bufA, b2, nullptr, p1Hi, p1Lo);
  }
  // ---- Layer 3: h3 = x2 @ W3 -> bufA; agg -> out (no ELU) ----
  {
    gemm_mfma_split<0><<<dim3(NCLS_P / 128, (NN + 127) / 128), 256, 0,
                         stream>>>(p1Hi, p1Lo, w3tHi, w3tLo, bufA, nullptr,
                                   nullptr, nullptr, NN, WIDTH, NCLS);
    compute_al<<<nwblk, 256, 0, stream>>>(bufA, a3_src, a3_dst, al_s, al_d,
                                          NN, 1, NCLS);
    csr_softmax<1><<<nwblk, 256, 0, stream>>>(rowptr, csrc, al_s, al_d,
                                              alpha);
    pull_agg<NCLS, false, false><<<nwblk, 256, 0, stream>>>(
        rowptr, csrc, alpha, bufA, b3, out, nullptr, nullptr);
  }
}

// Round 8
// 544.559 us; speedup vs baseline: 1.6490x; 1.1053x over previous
//
#include <hip/hip_runtime.h>
#include <hip/hip_bf16.h>

// Problem constants (match reference)
#define NN     20000
#define ERAW   320000
#define ETOT   (ERAW + NN)   // 340000 with self loops
#define F_IN   50
#define HID    64
#define HEADS  8
#define WIDTH  512           // HID*HEADS
#define NCLS   121
#define NCLS_P 128           // padded cols for layer-3 MFMA GEMM

typedef __attribute__((ext_vector_type(8))) __bf16 bf16x8;
typedef __attribute__((ext_vector_type(4))) float floatx4;

// ---------------- fp32 -> bf16 split helpers --------------------------------
__device__ __forceinline__ unsigned short f32_to_bf16_rn(float f) {
  unsigned u = __float_as_uint(f);
  unsigned r = u + 0x7fffu + ((u >> 16) & 1u);
  return (unsigned short)(r >> 16);
}
__device__ __forceinline__ void split_one(float f, unsigned short& h,
                                          unsigned short& l) {
  h = f32_to_bf16_rn(f);
  float fh = __uint_as_float(((unsigned)h) << 16);
  l = f32_to_bf16_rn(f - fh);
}

// W [K][M] fp32 -> Bt hi/lo [Mp][K] bf16 ushort (rows m>=M zero-padded)
__global__ __launch_bounds__(256) void transpose_split(
    const float* __restrict__ W, unsigned short* __restrict__ thi,
    unsigned short* __restrict__ tlo, int K, int M, int Mp) {
  __shared__ float t[32][33];
  int k0 = blockIdx.x * 32, m0 = blockIdx.y * 32;
  int tx = threadIdx.x & 31, ty = threadIdx.x >> 5;  // 32 x 8
  #pragma unroll
  for (int r = 0; r < 4; ++r) {
    int k = k0 + ty + r * 8, m = m0 + tx;
    float v = 0.f;
    if (k < K && m < M) v = W[(size_t)k * M + m];
    t[ty + r * 8][tx] = v;
  }
  __syncthreads();
  #pragma unroll
  for (int r = 0; r < 4; ++r) {
    int m = m0 + ty + r * 8, k = k0 + tx;
    if (m < Mp && k < K) {
      unsigned short h, l;
      split_one(t[tx][ty + r * 8], h, l);
      thi[(size_t)m * K + k] = h;
      tlo[(size_t)m * K + k] = l;
    }
  }
}

// Per-head W1 transposed split: w1h[hd][col(64)][k(64)], k>=50 zero.
__global__ __launch_bounds__(256) void build_w1h_t(
    const float* __restrict__ W1, unsigned short* __restrict__ thi,
    unsigned short* __restrict__ tlo) {
  int idx = blockIdx.x * blockDim.x + threadIdx.x;
  if (idx >= HEADS * HID * HID) return;
  int hd = idx >> 12, rem = idx & 4095;
  int col = rem >> 6, k = rem & 63;
  float v = (k < F_IN) ? W1[(size_t)k * WIDTH + hd * HID + col] : 0.f;
  unsigned short h, l;
  split_one(v, h, l);
  thi[idx] = h;
  tlo[idx] = l;
}

// ---- split-bf16 MFMA GEMM: C[N,M] = A[N,K] @ B[K,M] (B given as Bt[Mp][K]) -
__global__ __launch_bounds__(256) void gemm_mfma_split(
    const unsigned short* __restrict__ Ahi, const unsigned short* __restrict__ Alo,
    const unsigned short* __restrict__ Bthi, const unsigned short* __restrict__ Btlo,
    float* __restrict__ C, int N, int K, int M) {
  __shared__ unsigned short sAhi[4096], sAlo[4096], sBhi[4096], sBlo[4096];
  const int tid = threadIdx.x;
  const int wave = tid >> 6, lane = tid & 63;
  const int wr = wave >> 1, wc = wave & 1;
  const int r0 = blockIdx.y * 128;
  const int c0 = blockIdx.x * 128;
  const int lkg = lane >> 4;
  const int lmn = lane & 15;

  const int skg = tid & 3;
  const int srow = tid >> 2;
  int ra0 = r0 + srow;        if (ra0 > NN - 1) ra0 = NN - 1;
  int ra1 = r0 + srow + 64;   if (ra1 > NN - 1) ra1 = NN - 1;
  const unsigned short* gAhi0 = Ahi + (size_t)ra0 * K + skg * 8;
  const unsigned short* gAhi1 = Ahi + (size_t)ra1 * K + skg * 8;
  const unsigned short* gAlo0 = Alo + (size_t)ra0 * K + skg * 8;
  const unsigned short* gAlo1 = Alo + (size_t)ra1 * K + skg * 8;
  const unsigned short* gBhi0 = Bthi + (size_t)(c0 + srow) * K + skg * 8;
  const unsigned short* gBhi1 = Bthi + (size_t)(c0 + srow + 64) * K + skg * 8;
  const unsigned short* gBlo0 = Btlo + (size_t)(c0 + srow) * K + skg * 8;
  const unsigned short* gBlo1 = Btlo + (size_t)(c0 + srow + 64) * K + skg * 8;

  floatx4 acc[4][4] = {};

  uint4 a0, a1, a2, a3, b0, b1, b2, b3;
  auto gload = [&](int kk) {
    a0 = *(const uint4*)(gAhi0 + kk);
    a1 = *(const uint4*)(gAhi1 + kk);
    a2 = *(const uint4*)(gAlo0 + kk);
    a3 = *(const uint4*)(gAlo1 + kk);
    b0 = *(const uint4*)(gBhi0 + kk);
    b1 = *(const uint4*)(gBhi1 + kk);
    b2 = *(const uint4*)(gBlo0 + kk);
    b3 = *(const uint4*)(gBlo1 + kk);
  };
  gload(0);

  const int w0 = (skg * 128 + srow) * 8;
  const int w1 = (skg * 128 + srow + 64) * 8;

  for (int k0 = 0; k0 < K; k0 += 32) {
    __syncthreads();
    *(uint4*)(sAhi + w0) = a0;
    *(uint4*)(sAhi + w1) = a1;
    *(uint4*)(sAlo + w0) = a2;
    *(uint4*)(sAlo + w1) = a3;
    *(uint4*)(sBhi + w0) = b0;
    *(uint4*)(sBhi + w1) = b1;
    *(uint4*)(sBlo + w0) = b2;
    *(uint4*)(sBlo + w1) = b3;
    __syncthreads();
    if (k0 + 32 < K) gload(k0 + 32);

    bf16x8 fAhi[4], fAlo[4], fBhi[4], fBlo[4];
    #pragma unroll
    for (int mi = 0; mi < 4; ++mi) {
      int m = wr * 64 + mi * 16 + lmn;
      fAhi[mi] = *(const bf16x8*)(sAhi + (lkg * 128 + m) * 8);
      fAlo[mi] = *(const bf16x8*)(sAlo + (lkg * 128 + m) * 8);
    }
    #pragma unroll
    for (int ni = 0; ni < 4; ++ni) {
      int n = wc * 64 + ni * 16 + lmn;
      fBhi[ni] = *(const bf16x8*)(sBhi + (lkg * 128 + n) * 8);
      fBlo[ni] = *(const bf16x8*)(sBlo + (lkg * 128 + n) * 8);
    }
    #pragma unroll
    for (int mi = 0; mi < 4; ++mi)
      #pragma unroll
      for (int ni = 0; ni < 4; ++ni) {
        acc[mi][ni] = __builtin_amdgcn_mfma_f32_16x16x32_bf16(
            fAhi[mi], fBhi[ni], acc[mi][ni], 0, 0, 0);
        acc[mi][ni] = __builtin_amdgcn_mfma_f32_16x16x32_bf16(
            fAhi[mi], fBlo[ni], acc[mi][ni], 0, 0, 0);
        acc[mi][ni] = __builtin_amdgcn_mfma_f32_16x16x32_bf16(
            fAlo[mi], fBhi[ni], acc[mi][ni], 0, 0, 0);
      }
  }

  #pragma unroll
  for (int mi = 0; mi < 4; ++mi) {
    #pragma unroll
    for (int r = 0; r < 4; ++r) {
      int grow = r0 + wr * 64 + mi * 16 + (lane >> 4) * 4 + r;
      if (grow >= N) continue;
      #pragma unroll
      for (int ni = 0; ni < 4; ++ni) {
        int gcol = c0 + wc * 64 + ni * 16 + lmn;
        if (gcol < M) C[(size_t)grow * M + gcol] = acc[mi][ni][r];
      }
    }
  }
}

// ---- batched per-head L1 GEMM: C[n,hd*64+c] = elu(A[n,hd*64+:64]@W1h + b1) -
// grid (ceil(NN/128), 8). Tile 128 rows x 64 cols, K=64 one-shot.
__global__ __launch_bounds__(256) void gemm_l1_heads(
    const unsigned short* __restrict__ Ahi, const unsigned short* __restrict__ Alo,
    const unsigned short* __restrict__ Bthi, const unsigned short* __restrict__ Btlo,
    unsigned short* __restrict__ outHi, unsigned short* __restrict__ outLo,
    const float* __restrict__ bias) {
  // LDS: sA [kseg2][lkg4][row128][8] ; sB [kseg2][lkg4][col64][8]
  __shared__ unsigned short sAhi[8192], sAlo[8192], sBhi[4096], sBlo[4096];
  const int tid = threadIdx.x;
  const int wave = tid >> 6, lane = tid & 63;
  const int r0 = blockIdx.x * 128;
  const int hd = blockIdx.y;
  const int lkg = lane >> 4, lmn = lane & 15;

  // stage A: 128 rows x 8 chunks(16B each, k=c*8..c*8+7); 1024 chunks
  #pragma unroll
  for (int t = 0; t < 4; ++t) {
    int cid = tid + t * 256;
    int row = cid >> 3, c = cid & 7;
    int gr = r0 + row; if (gr > NN - 1) gr = NN - 1;
    const size_t goff = (size_t)gr * WIDTH + hd * HID + c * 8;
    int loff = (((c >> 2) * 4 + (c & 3)) * 128 + row) * 8;
    *(uint4*)(sAhi + loff) = *(const uint4*)(Ahi + goff);
    *(uint4*)(sAlo + loff) = *(const uint4*)(Alo + goff);
  }
  // stage B: 64 cols x 8 chunks; 512 chunks
  #pragma unroll
  for (int t = 0; t < 2; ++t) {
    int cid = tid + t * 256;
    int col = cid >> 3, c = cid & 7;
    const size_t goff = (size_t)(hd * HID + col) * HID + c * 8;
    int loff = (((c >> 2) * 4 + (c & 3)) * 64 + col) * 8;
    *(uint4*)(sBhi + loff) = *(const uint4*)(Bthi + goff);
    *(uint4*)(sBlo + loff) = *(const uint4*)(Btlo + goff);
  }
  __syncthreads();

  floatx4 acc[2][4] = {};
  #pragma unroll
  for (int ks = 0; ks < 2; ++ks) {
    bf16x8 fAhi[2], fAlo[2], fBhi[4], fBlo[4];
    #pragma unroll
    for (int mi = 0; mi < 2; ++mi) {
      int m = wave * 32 + mi * 16 + lmn;
      int off = ((ks * 4 + lkg) * 128 + m) * 8;
      fAhi[mi] = *(const bf16x8*)(sAhi + off);
      fAlo[mi] = *(const bf16x8*)(sAlo + off);
    }
    #pragma unroll
    for (int ni = 0; ni < 4; ++ni) {
      int n = ni * 16 + lmn;
      int off = ((ks * 4 + lkg) * 64 + n) * 8;
      fBhi[ni] = *(const bf16x8*)(sBhi + off);
      fBlo[ni] = *(const bf16x8*)(sBlo + off);
    }
    #pragma unroll
    for (int mi = 0; mi < 2; ++mi)
      #pragma unroll
      for (int ni = 0; ni < 4; ++ni) {
        acc[mi][ni] = __builtin_amdgcn_mfma_f32_16x16x32_bf16(
            fAhi[mi], fBhi[ni], acc[mi][ni], 0, 0, 0);
        acc[mi][ni] = __builtin_amdgcn_mfma_f32_16x16x32_bf16(
            fAhi[mi], fBlo[ni], acc[mi][ni], 0, 0, 0);
        acc[mi][ni] = __builtin_amdgcn_mfma_f32_16x16x32_bf16(
            fAlo[mi], fBhi[ni], acc[mi][ni], 0, 0, 0);
      }
  }

  #pragma unroll
  for (int mi = 0; mi < 2; ++mi) {
    #pragma unroll
    for (int r = 0; r < 4; ++r) {
      int grow = r0 + wave * 32 + mi * 16 + (lane >> 4) * 4 + r;
      if (grow >= NN) continue;
      #pragma unroll
      for (int ni = 0; ni < 4; ++ni) {
        int gcol = hd * HID + ni * 16 + lmn;
        float v = acc[mi][ni][r] + bias[gcol];
        v = (v > 0.f) ? v : (__expf(v) - 1.0f);
        unsigned short hh, ll;
        split_one(v, hh, ll);
        outHi[(size_t)grow * WIDTH + gcol] = hh;
        outLo[(size_t)grow * WIDTH + gcol] = ll;
      }
    }
  }
}

// ---------------- layer-1 folded attention weights --------------------------
__global__ __launch_bounds__(256) void fold_w1a(
    const float* __restrict__ W1, const float* __restrict__ a1s,
    const float* __restrict__ a1d, float* __restrict__ w1as,
    float* __restrict__ w1ad) {
  int idx = blockIdx.x * blockDim.x + threadIdx.x;
  if (idx >= 2 * F_IN * HEADS) return;
  int which = idx >= F_IN * HEADS;
  int r = which ? idx - F_IN * HEADS : idx;
  int k = r >> 3, h = r & 7;
  const float* a = which ? a1d : a1s;
  float s = 0.f;
  for (int c = 0; c < HID; ++c) s += W1[(size_t)k * WIDTH + h * HID + c] * a[h * HID + c];
  (which ? w1ad : w1as)[r] = s;
}

// al1[n,h] = sum_k x[n,k] * w1a[k,h]   (one wave per node)
__global__ __launch_bounds__(256) void al1_kernel(
    const float* __restrict__ x, const float* __restrict__ w1as,
    const float* __restrict__ w1ad, float* __restrict__ al_s,
    float* __restrict__ al_d) {
  int n = (blockIdx.x * blockDim.x + threadIdx.x) >> 6;
  int lane = threadIdx.x & 63;
  if (n >= NN) return;
  float xv = (lane < F_IN) ? x[(size_t)n * F_IN + lane] : 0.f;
  float ws[HEADS], wd[HEADS];
  #pragma unroll
  for (int h = 0; h < HEADS; ++h) {
    ws[h] = (lane < F_IN) ? w1as[lane * HEADS + h] : 0.f;
    wd[h] = (lane < F_IN) ? w1ad[lane * HEADS + h] : 0.f;
  }
  #pragma unroll
  for (int h = 0; h < HEADS; ++h) {
    float ss = xv * ws[h], sd = xv * wd[h];
    #pragma unroll
    for (int o = 32; o; o >>= 1) {
      ss += __shfl_xor(ss, o);
      sd += __shfl_xor(sd, o);
    }
    if (lane == 0) {
      al_s[n * HEADS + h] = ss;
      al_d[n * HEADS + h] = sd;
    }
  }
}

// ---------------- per-node attention logits (from h; H=1 layers) -----------
__global__ __launch_bounds__(256) void compute_al(
    const float* __restrict__ h, const float* __restrict__ a_src,
    const float* __restrict__ a_dst, float* __restrict__ al_s,
    float* __restrict__ al_d, int Nn, int H, int C) {
  int wave = (blockIdx.x * blockDim.x + threadIdx.x) >> 6;
  int lane = threadIdx.x & 63;
  if (wave >= Nn) return;
  const float* hr = h + (size_t)wave * H * C;
  for (int hd = 0; hd < H; ++hd) {
    float ss = 0.f, sd = 0.f;
    for (int c = lane; c < C; c += 64) {
      float v = hr[hd * C + c];
      ss += v * a_src[hd * C + c];
      sd += v * a_dst[hd * C + c];
    }
    #pragma unroll
    for (int o = 32; o; o >>= 1) {
      ss += __shfl_xor(ss, o);
      sd += __shfl_xor(sd, o);
    }
    if (lane == 0) {
      al_s[wave * H + hd] = ss;
      al_d[wave * H + hd] = sd;
    }
  }
}

// ---------------- CSR build (once; shared by all layers) --------------------
__global__ __launch_bounds__(256) void count_deg(
    const int* __restrict__ edst, int* __restrict__ deg) {
  int e = blockIdx.x * blockDim.x + threadIdx.x;
  if (e >= ETOT) return;
  int d = (e < ERAW) ? edst[e] : (e - ERAW);
  atomicAdd(&deg[d], 1);
}

__global__ __launch_bounds__(256) void scan_deg(
    const int* __restrict__ deg, int* __restrict__ rowptr) {
  __shared__ int part[256];
  const int t = threadIdx.x;
  const int CHUNK = (NN + 255) / 256;
  int lo = t * CHUNK, hi = min(lo + CHUNK, NN);
  int s = 0;
  for (int i = lo; i < hi; ++i) s += deg[i];
  part[t] = s;
  __syncthreads();
  for (int off = 1; off < 256; off <<= 1) {
    int v = (t >= off) ? part[t - off] : 0;
    __syncthreads();
    part[t] += v;
    __syncthreads();
  }
  int base = (t == 0) ? 0 : part[t - 1];
  for (int i = lo; i < hi; ++i) {
    rowptr[i] = base;
    base += deg[i];
  }
  if (t == 255) rowptr[NN] = part[255];
}

__global__ __launch_bounds__(256) void scatter_csr(
    const int* __restrict__ esrc, const int* __restrict__ edst,
    const int* __restrict__ rowptr, int* __restrict__ cnt,
    int* __restrict__ csrc) {
  int e = blockIdx.x * blockDim.x + threadIdx.x;
  if (e >= ETOT) return;
  int s, d;
  if (e < ERAW) { s = esrc[e]; d = edst[e]; }
  else          { s = e - ERAW; d = e - ERAW; }
  int pos = rowptr[d] + atomicAdd(&cnt[d], 1);
  csrc[pos] = s;
}

// ---- CSR-order edge softmax (8-head, layer 1 only) ------------------------
template <int H>
__global__ __launch_bounds__(256) void csr_softmax(
    const int* __restrict__ rowptr, const int* __restrict__ csrc,
    const float* __restrict__ al_s, const float* __restrict__ al_d,
    float* __restrict__ alpha) {
  const int w = threadIdx.x >> 6, lane = threadIdx.x & 63;
  const int d = blockIdx.x * 4 + w;
  if (d >= NN) return;
  const int r0 = rowptr[d], r1 = rowptr[d + 1];
  float ald[H];
  #pragma unroll
  for (int h = 0; h < H; ++h) ald[h] = al_d[d * H + h];

  float mx[H];
  #pragma unroll
  for (int h = 0; h < H; ++h) mx[h] = -3.4e38f;
  for (int p = r0 + lane; p < r1; p += 64) {
    int s = csrc[p];
    #pragma unroll
    for (int h = 0; h < H; ++h) {
      float v = al_s[s * H + h] + ald[h];
      v = (v > 0.f) ? v : 0.2f * v;
      mx[h] = fmaxf(mx[h], v);
    }
  }
  #pragma unroll
  for (int o = 32; o; o >>= 1)
    #pragma unroll
    for (int h = 0; h < H; ++h) mx[h] = fmaxf(mx[h], __shfl_xor(mx[h], o));

  float zs[H];
  #pragma unroll
  for (int h = 0; h < H; ++h) zs[h] = 0.f;
  for (int p = r0 + lane; p < r1; p += 64) {
    int s = csrc[p];
    #pragma unroll
    for (int h = 0; h < H; ++h) {
      float v = al_s[s * H + h] + ald[h];
      v = (v > 0.f) ? v : 0.2f * v;
      float e = __expf(v - mx[h]);
      alpha[(size_t)p * H + h] = e;
      zs[h] += e;
    }
  }
  #pragma unroll
  for (int o = 32; o; o >>= 1)
    #pragma unroll
    for (int h = 0; h < H; ++h) zs[h] += __shfl_xor(zs[h], o);
  float iz[H];
  #pragma unroll
  for (int h = 0; h < H; ++h) iz[h] = 1.0f / (zs[h] + 1e-16f);

  for (int p = r0 + lane; p < r1; p += 64) {
    #pragma unroll
    for (int h = 0; h < H; ++h) alpha[(size_t)p * H + h] *= iz[h];
  }
}

// ---- layer-1: aggregate raw x per head; write bf16-split PADDED [NN,512] --
__global__ __launch_bounds__(256) void agg_x(
    const int* __restrict__ rowptr, const int* __restrict__ csrc,
    const float* __restrict__ alpha, const float* __restrict__ x,
    unsigned short* __restrict__ outHi, unsigned short* __restrict__ outLo) {
  const int w = threadIdx.x >> 6, lane = threadIdx.x & 63;
  const int d = blockIdx.x * 4 + w;
  if (d >= NN) return;
  const int r0 = rowptr[d], r1 = rowptr[d + 1];
  float acc[HEADS];
  #pragma unroll
  for (int h = 0; h < HEADS; ++h) acc[h] = 0.f;
  for (int p = r0; p < r1; ++p) {
    int s = csrc[p];
    float av = alpha[(size_t)p * HEADS + (lane & 7)];
    float xv = (lane < F_IN) ? x[(size_t)s * F_IN + lane] : 0.f;
    #pragma unroll
    for (int h = 0; h < HEADS; ++h) acc[h] += __shfl(av, h, 8) * xv;
  }
  #pragma unroll
  for (int h = 0; h < HEADS; ++h) {
    float v = (lane < F_IN) ? acc[h] : 0.f;
    unsigned short hh, ll;
    split_one(v, hh, ll);
    outHi[(size_t)d * WIDTH + h * HID + lane] = hh;
    outLo[(size_t)d * WIDTH + h * HID + lane] = ll;
  }
}

// ---- fused softmax + pull aggregation (H=1), wave per dst -----------------
// alpha recomputed inline: v=lrelu(al_s[src]+al_d[d]); a=exp(v-max)/z.
template <int M, bool ELU, bool SPLIT>
__global__ __launch_bounds__(256) void pull_agg_sm(
    const int* __restrict__ rowptr, const int* __restrict__ csrc,
    const float* __restrict__ al_s, const float* __restrict__ al_d,
    const float* __restrict__ h, const float* __restrict__ bias,
    float* __restrict__ out, unsigned short* __restrict__ outHi,
    unsigned short* __restrict__ outLo) {
  constexpr int EPL = (M + 63) / 64;
  const int w = threadIdx.x >> 6;
  const int lane = threadIdx.x & 63;
  const int d = blockIdx.x * 4 + w;
  if (d >= NN) return;
  const int r0 = rowptr[d], r1 = rowptr[d + 1];
  const float ald = al_d[d];

  // pass 1: max
  float mx = -3.4e38f;
  for (int p = r0 + lane; p < r1; p += 64) {
    float v = al_s[csrc[p]] + ald;
    v = (v > 0.f) ? v : 0.2f * v;
    mx = fmaxf(mx, v);
  }
  #pragma unroll
  for (int o = 32; o; o >>= 1) mx = fmaxf(mx, __shfl_xor(mx, o));
  // pass 2: z
  float zs = 0.f;
  for (int p = r0 + lane; p < r1; p += 64) {
    float v = al_s[csrc[p]] + ald;
    v = (v > 0.f) ? v : 0.2f * v;
    zs += __expf(v - mx);
  }
  #pragma unroll
  for (int o = 32; o; o >>= 1) zs += __shfl_xor(zs, o);
  const float iz = 1.0f / (zs + 1e-16f);

  // pass 3: aggregate (all lanes walk same edge; each owns EPL cols)
  const int base = lane * EPL;
  float acc[EPL];
  #pragma unroll
  for (int j = 0; j < EPL; ++j) acc[j] = 0.f;
  for (int p = r0; p < r1; ++p) {
    int s = csrc[p];
    float v = al_s[s] + ald;            // broadcast load
    v = (v > 0.f) ? v : 0.2f * v;
    float a = __expf(v - mx) * iz;
    const float* hr = h + (size_t)s * M + base;
    #pragma unroll
    for (int j = 0; j < EPL; ++j) {
      if ((M % 64 == 0) || (base + j < M)) acc[j] += hr[j] * a;
    }
  }

  #pragma unroll
  for (int j = 0; j < EPL; ++j) {
    if ((M % 64 == 0) || (base + j < M)) {
      float v = acc[j] + bias[base + j];
      if (ELU) v = (v > 0.f) ? v : (__expf(v) - 1.0f);
      if (SPLIT) {
        unsigned short hh, ll;
        split_one(v, hh, ll);
        outHi[(size_t)d * M + base + j] = hh;
        outLo[(size_t)d * M + base + j] = ll;
      } else {
        out[(size_t)d * M + base + j] = v;
      }
    }
  }
}

extern "C" void kernel_launch(void* const* d_in, const int* in_sizes, int n_in,
                              void* d_out, int out_size, void* d_ws,
                              size_t ws_size, hipStream_t stream) {
  const float* x      = (const float*)d_in[0];
  const int*   ei     = (const int*)d_in[1];
  const float* W1     = (const float*)d_in[2];
  const float* a1_src = (const float*)d_in[3];
  const float* a1_dst = (const float*)d_in[4];
  const float* b1     = (const float*)d_in[5];
  const float* W2     = (const float*)d_in[6];
  const float* a2_src = (const float*)d_in[7];
  const float* a2_dst = (const float*)d_in[8];
  const float* b2     = (const float*)d_in[9];
  const float* W3     = (const float*)d_in[10];
  const float* a3_src = (const float*)d_in[11];
  const float* a3_dst = (const float*)d_in[12];
  const float* b3     = (const float*)d_in[13];
  float* out = (float*)d_out;

  const int* esrc = ei;
  const int* edst = ei + ERAW;

  // Workspace carve-up
  unsigned short* p1Hi  = (unsigned short*)d_ws;          // NN*WIDTH
  unsigned short* p1Lo  = p1Hi + (size_t)NN * WIDTH;
  unsigned short* p2Hi  = p1Lo + (size_t)NN * WIDTH;
  unsigned short* p2Lo  = p2Hi + (size_t)NN * WIDTH;
  unsigned short* w1hHi = p2Lo + (size_t)NN * WIDTH;      // 8*64*64
  unsigned short* w1hLo = w1hHi + (size_t)HEADS * HID * HID;
  unsigned short* w2tHi = w1hLo + (size_t)HEADS * HID * HID;  // 512*512
  unsigned short* w2tLo = w2tHi + (size_t)WIDTH * WIDTH;
  unsigned short* w3tHi = w2tLo + (size_t)WIDTH * WIDTH;  // 128*512
  unsigned short* w3tLo = w3tHi + (size_t)NCLS_P * WIDTH;
  float* bufA   = (float*)(w3tLo + (size_t)NCLS_P * WIDTH);  // NN*WIDTH (h)
  float* alpha  = bufA + (size_t)NN * WIDTH;              // ETOT*HEADS (L1)
  float* al_s   = alpha + (size_t)ETOT * HEADS;
  float* al_d   = al_s + (size_t)NN * HEADS;
  float* w1as   = al_d + (size_t)NN * HEADS;              // 50*8
  float* w1ad   = w1as + F_IN * HEADS;
  int* deg      = (int*)(w1ad + F_IN * HEADS);
  int* rowptr   = deg + NN;
  int* cnt      = rowptr + NN + 4;
  int* csrc     = cnt + NN;                               // ETOT

  // ---- build CSR by destination (once) ----
  hipMemsetAsync(deg, 0, (size_t)NN * sizeof(int), stream);
  hipMemsetAsync(cnt, 0, (size_t)NN * sizeof(int), stream);
  const int eblk = (ETOT + 255) / 256;
  count_deg<<<eblk, 256, 0, stream>>>(edst, deg);
  scan_deg<<<1, 256, 0, stream>>>(deg, rowptr);
  scatter_csr<<<eblk, 256, 0, stream>>>(esrc, edst, rowptr, cnt, csrc);

  // ---- weight prep (once) ----
  build_w1h_t<<<(HEADS * HID * HID + 255) / 256, 256, 0, stream>>>(W1, w1hHi,
                                                                   w1hLo);
  transpose_split<<<dim3(WIDTH / 32, WIDTH / 32), 256, 0, stream>>>(
      W2, w2tHi, w2tLo, WIDTH, WIDTH, WIDTH);
  transpose_split<<<dim3(WIDTH / 32, NCLS_P / 32), 256, 0, stream>>>(
      W3, w3tHi, w3tLo, WIDTH, NCLS, NCLS_P);

  const int nwblk = (NN + 3) / 4;

  // ---- Layer 1 (aggregate-x-first; batched per-head MFMA GEMM) ----
  {
    fold_w1a<<<(2 * F_IN * HEADS + 255) / 256, 256, 0, stream>>>(
        W1, a1_src, a1_dst, w1as, w1ad);
    al1_kernel<<<nwblk, 256, 0, stream>>>(x, w1as, w1ad, al_s, al_d);
    csr_softmax<HEADS><<<nwblk, 256, 0, stream>>>(rowptr, csrc, al_s, al_d,
                                                  alpha);
    agg_x<<<nwblk, 256, 0, stream>>>(rowptr, csrc, alpha, x, p1Hi, p1Lo);
    gemm_l1_heads<<<dim3((NN + 127) / 128, HEADS), 256, 0, stream>>>(
        p1Hi, p1Lo, w1hHi, w1hLo, p2Hi, p2Lo, b1);
  }
  // ---- Layer 2: h2 = x1 @ W2 -> bufA fp32; fused softmax-agg -> P1 split --
  {
    gemm_mfma_split<<<dim3(WIDTH / 128, (NN + 127) / 128), 256, 0, stream>>>(
        p2Hi, p2Lo, w2tHi, w2tLo, bufA, NN, WIDTH, WIDTH);
    compute_al<<<nwblk, 256, 0, stream>>>(bufA, a2_src, a2_dst, al_s, al_d,
                                          NN, 1, WIDTH);
    pull_agg_sm<WIDTH, true, true><<<nwblk, 256, 0, stream>>>(
        rowptr, csrc, al_s, al_d, bufA, b2, nullptr, p1Hi, p1Lo);
  }
  // ---- Layer 3: h3 = x2 @ W3 -> bufA; fused softmax-agg -> out (no ELU) ---
  {
    gemm_mfma_split<<<dim3(NCLS_P / 128, (NN + 127) / 128), 256, 0, stream>>>(
        p1Hi, p1Lo, w3tHi, w3tLo, bufA, NN, WIDTH, NCLS);
    compute_al<<<nwblk, 256, 0, stream>>>(bufA, a3_src, a3_dst, al_s, al_d,
                                          NN, 1, NCLS);
    pull_agg_sm<NCLS, false, false><<<nwblk, 256, 0, stream>>>(
        rowptr, csrc, al_s, al_d, bufA, b3, out, nullptr, nullptr);
  }
}

// Round 9
// 534.980 us; speedup vs baseline: 1.6785x; 1.0179x over previous
//
#include <hip/hip_runtime.h>
#include <hip/hip_bf16.h>

// Problem constants (match reference)
#define NN     20000
#define ERAW   320000
#define ETOT   (ERAW + NN)   // 340000 with self loops
#define F_IN   50
#define HID    64
#define HEADS  8
#define WIDTH  512           // HID*HEADS
#define NCLS   121
#define NCLS_P 128           // padded cols for layer-3 MFMA GEMM

typedef __attribute__((ext_vector_type(8))) __bf16 bf16x8;
typedef __attribute__((ext_vector_type(4))) float floatx4;

// ---------------- fp32 -> bf16 split helpers --------------------------------
__device__ __forceinline__ unsigned short f32_to_bf16_rn(float f) {
  unsigned u = __float_as_uint(f);
  unsigned r = u + 0x7fffu + ((u >> 16) & 1u);
  return (unsigned short)(r >> 16);
}
__device__ __forceinline__ void split_one(float f, unsigned short& h,
                                          unsigned short& l) {
  h = f32_to_bf16_rn(f);
  float fh = __uint_as_float(((unsigned)h) << 16);
  l = f32_to_bf16_rn(f - fh);
}

// select arr[i] from an unrolled register array (no scratch)
__device__ __forceinline__ float sel8(const float* a, int i) {
  float r = a[0];
  #pragma unroll
  for (int h = 1; h < 8; ++h) r = (i == h) ? a[h] : r;
  return r;
}

// W [K][M] fp32 -> Bt hi/lo [Mp][K] bf16 ushort (rows m>=M zero-padded)
__global__ __launch_bounds__(256) void transpose_split(
    const float* __restrict__ W, unsigned short* __restrict__ thi,
    unsigned short* __restrict__ tlo, int K, int M, int Mp) {
  __shared__ float t[32][33];
  int k0 = blockIdx.x * 32, m0 = blockIdx.y * 32;
  int tx = threadIdx.x & 31, ty = threadIdx.x >> 5;  // 32 x 8
  #pragma unroll
  for (int r = 0; r < 4; ++r) {
    int k = k0 + ty + r * 8, m = m0 + tx;
    float v = 0.f;
    if (k < K && m < M) v = W[(size_t)k * M + m];
    t[ty + r * 8][tx] = v;
  }
  __syncthreads();
  #pragma unroll
  for (int r = 0; r < 4; ++r) {
    int m = m0 + ty + r * 8, k = k0 + tx;
    if (m < Mp && k < K) {
      unsigned short h, l;
      split_one(t[tx][ty + r * 8], h, l);
      thi[(size_t)m * K + k] = h;
      tlo[(size_t)m * K + k] = l;
    }
  }
}

// Per-head W1 transposed split: w1h[hd][col(64)][k(64)], k>=50 zero.
__global__ __launch_bounds__(256) void build_w1h_t(
    const float* __restrict__ W1, unsigned short* __restrict__ thi,
    unsigned short* __restrict__ tlo) {
  int idx = blockIdx.x * blockDim.x + threadIdx.x;
  if (idx >= HEADS * HID * HID) return;
  int hd = idx >> 12, rem = idx & 4095;
  int col = rem >> 6, k = rem & 63;
  float v = (k < F_IN) ? W1[(size_t)k * WIDTH + hd * HID + col] : 0.f;
  unsigned short h, l;
  split_one(v, h, l);
  thi[idx] = h;
  tlo[idx] = l;
}

// ---- split-bf16 MFMA GEMM: C[N,M] = A[N,K] @ B[K,M] (B given as Bt[Mp][K]) -
__global__ __launch_bounds__(256) void gemm_mfma_split(
    const unsigned short* __restrict__ Ahi, const unsigned short* __restrict__ Alo,
    const unsigned short* __restrict__ Bthi, const unsigned short* __restrict__ Btlo,
    float* __restrict__ C, int N, int K, int M) {
  __shared__ unsigned short sAhi[4096], sAlo[4096], sBhi[4096], sBlo[4096];
  const int tid = threadIdx.x;
  const int wave = tid >> 6, lane = tid & 63;
  const int wr = wave >> 1, wc = wave & 1;
  const int r0 = blockIdx.y * 128;
  const int c0 = blockIdx.x * 128;
  const int lkg = lane >> 4;
  const int lmn = lane & 15;

  const int skg = tid & 3;
  const int srow = tid >> 2;
  int ra0 = r0 + srow;        if (ra0 > NN - 1) ra0 = NN - 1;
  int ra1 = r0 + srow + 64;   if (ra1 > NN - 1) ra1 = NN - 1;
  const unsigned short* gAhi0 = Ahi + (size_t)ra0 * K + skg * 8;
  const unsigned short* gAhi1 = Ahi + (size_t)ra1 * K + skg * 8;
  const unsigned short* gAlo0 = Alo + (size_t)ra0 * K + skg * 8;
  const unsigned short* gAlo1 = Alo + (size_t)ra1 * K + skg * 8;
  const unsigned short* gBhi0 = Bthi + (size_t)(c0 + srow) * K + skg * 8;
  const unsigned short* gBhi1 = Bthi + (size_t)(c0 + srow + 64) * K + skg * 8;
  const unsigned short* gBlo0 = Btlo + (size_t)(c0 + srow) * K + skg * 8;
  const unsigned short* gBlo1 = Btlo + (size_t)(c0 + srow + 64) * K + skg * 8;

  floatx4 acc[4][4] = {};

  uint4 a0, a1, a2, a3, b0, b1, b2, b3;
  auto gload = [&](int kk) {
    a0 = *(const uint4*)(gAhi0 + kk);
    a1 = *(const uint4*)(gAhi1 + kk);
    a2 = *(const uint4*)(gAlo0 + kk);
    a3 = *(const uint4*)(gAlo1 + kk);
    b0 = *(const uint4*)(gBhi0 + kk);
    b1 = *(const uint4*)(gBhi1 + kk);
    b2 = *(const uint4*)(gBlo0 + kk);
    b3 = *(const uint4*)(gBlo1 + kk);
  };
  gload(0);

  const int w0 = (skg * 128 + srow) * 8;
  const int w1 = (skg * 128 + srow + 64) * 8;

  for (int k0 = 0; k0 < K; k0 += 32) {
    __syncthreads();
    *(uint4*)(sAhi + w0) = a0;
    *(uint4*)(sAhi + w1) = a1;
    *(uint4*)(sAlo + w0) = a2;
    *(uint4*)(sAlo + w1) = a3;
    *(uint4*)(sBhi + w0) = b0;
    *(uint4*)(sBhi + w1) = b1;
    *(uint4*)(sBlo + w0) = b2;
    *(uint4*)(sBlo + w1) = b3;
    __syncthreads();
    if (k0 + 32 < K) gload(k0 + 32);

    bf16x8 fAhi[4], fAlo[4], fBhi[4], fBlo[4];
    #pragma unroll
    for (int mi = 0; mi < 4; ++mi) {
      int m = wr * 64 + mi * 16 + lmn;
      fAhi[mi] = *(const bf16x8*)(sAhi + (lkg * 128 + m) * 8);
      fAlo[mi] = *(const bf16x8*)(sAlo + (lkg * 128 + m) * 8);
    }
    #pragma unroll
    for (int ni = 0; ni < 4; ++ni) {
      int n = wc * 64 + ni * 16 + lmn;
      fBhi[ni] = *(const bf16x8*)(sBhi + (lkg * 128 + n) * 8);
      fBlo[ni] = *(const bf16x8*)(sBlo + (lkg * 128 + n) * 8);
    }
    #pragma unroll
    for (int mi = 0; mi < 4; ++mi)
      #pragma unroll
      for (int ni = 0; ni < 4; ++ni) {
        acc[mi][ni] = __builtin_amdgcn_mfma_f32_16x16x32_bf16(
            fAhi[mi], fBhi[ni], acc[mi][ni], 0, 0, 0);
        acc[mi][ni] = __builtin_amdgcn_mfma_f32_16x16x32_bf16(
            fAhi[mi], fBlo[ni], acc[mi][ni], 0, 0, 0);
        acc[mi][ni] = __builtin_amdgcn_mfma_f32_16x16x32_bf16(
            fAlo[mi], fBhi[ni], acc[mi][ni], 0, 0, 0);
      }
  }

  #pragma unroll
  for (int mi = 0; mi < 4; ++mi) {
    #pragma unroll
    for (int r = 0; r < 4; ++r) {
      int grow = r0 + wr * 64 + mi * 16 + (lane >> 4) * 4 + r;
      if (grow >= N) continue;
      #pragma unroll
      for (int ni = 0; ni < 4; ++ni) {
        int gcol = c0 + wc * 64 + ni * 16 + lmn;
        if (gcol < M) C[(size_t)grow * M + gcol] = acc[mi][ni][r];
      }
    }
  }
}

// ---- batched per-head L1 GEMM: C[n,hd*64+c] = elu(A[n,hd*64+:64]@W1h + b1) -
__global__ __launch_bounds__(256) void gemm_l1_heads(
    const unsigned short* __restrict__ Ahi, const unsigned short* __restrict__ Alo,
    const unsigned short* __restrict__ Bthi, const unsigned short* __restrict__ Btlo,
    unsigned short* __restrict__ outHi, unsigned short* __restrict__ outLo,
    const float* __restrict__ bias) {
  __shared__ unsigned short sAhi[8192], sAlo[8192], sBhi[4096], sBlo[4096];
  const int tid = threadIdx.x;
  const int wave = tid >> 6, lane = tid & 63;
  const int r0 = blockIdx.x * 128;
  const int hd = blockIdx.y;
  const int lkg = lane >> 4, lmn = lane & 15;

  #pragma unroll
  for (int t = 0; t < 4; ++t) {
    int cid = tid + t * 256;
    int row = cid >> 3, c = cid & 7;
    int gr = r0 + row; if (gr > NN - 1) gr = NN - 1;
    const size_t goff = (size_t)gr * WIDTH + hd * HID + c * 8;
    int loff = (((c >> 2) * 4 + (c & 3)) * 128 + row) * 8;
    *(uint4*)(sAhi + loff) = *(const uint4*)(Ahi + goff);
    *(uint4*)(sAlo + loff) = *(const uint4*)(Alo + goff);
  }
  #pragma unroll
  for (int t = 0; t < 2; ++t) {
    int cid = tid + t * 256;
    int col = cid >> 3, c = cid & 7;
    const size_t goff = (size_t)(hd * HID + col) * HID + c * 8;
    int loff = (((c >> 2) * 4 + (c & 3)) * 64 + col) * 8;
    *(uint4*)(sBhi + loff) = *(const uint4*)(Bthi + goff);
    *(uint4*)(sBlo + loff) = *(const uint4*)(Btlo + goff);
  }
  __syncthreads();

  floatx4 acc[2][4] = {};
  #pragma unroll
  for (int ks = 0; ks < 2; ++ks) {
    bf16x8 fAhi[2], fAlo[2], fBhi[4], fBlo[4];
    #pragma unroll
    for (int mi = 0; mi < 2; ++mi) {
      int m = wave * 32 + mi * 16 + lmn;
      int off = ((ks * 4 + lkg) * 128 + m) * 8;
      fAhi[mi] = *(const bf16x8*)(sAhi + off);
      fAlo[mi] = *(const bf16x8*)(sAlo + off);
    }
    #pragma unroll
    for (int ni = 0; ni < 4; ++ni) {
      int n = ni * 16 + lmn;
      int off = ((ks * 4 + lkg) * 64 + n) * 8;
      fBhi[ni] = *(const bf16x8*)(sBhi + off);
      fBlo[ni] = *(const bf16x8*)(sBlo + off);
    }
    #pragma unroll
    for (int mi = 0; mi < 2; ++mi)
      #pragma unroll
      for (int ni = 0; ni < 4; ++ni) {
        acc[mi][ni] = __builtin_amdgcn_mfma_f32_16x16x32_bf16(
            fAhi[mi], fBhi[ni], acc[mi][ni], 0, 0, 0);
        acc[mi][ni] = __builtin_amdgcn_mfma_f32_16x16x32_bf16(
            fAhi[mi], fBlo[ni], acc[mi][ni], 0, 0, 0);
        acc[mi][ni] = __builtin_amdgcn_mfma_f32_16x16x32_bf16(
            fAlo[mi], fBhi[ni], acc[mi][ni], 0, 0, 0);
      }
  }

  #pragma unroll
  for (int mi = 0; mi < 2; ++mi) {
    #pragma unroll
    for (int r = 0; r < 4; ++r) {
      int grow = r0 + wave * 32 + mi * 16 + (lane >> 4) * 4 + r;
      if (grow >= NN) continue;
      #pragma unroll
      for (int ni = 0; ni < 4; ++ni) {
        int gcol = hd * HID + ni * 16 + lmn;
        float v = acc[mi][ni][r] + bias[gcol];
        v = (v > 0.f) ? v : (__expf(v) - 1.0f);
        unsigned short hh, ll;
        split_one(v, hh, ll);
        outHi[(size_t)grow * WIDTH + gcol] = hh;
        outLo[(size_t)grow * WIDTH + gcol] = ll;
      }
    }
  }
}

// ---------------- layer-1 folded attention weights --------------------------
__global__ __launch_bounds__(256) void fold_w1a(
    const float* __restrict__ W1, const float* __restrict__ a1s,
    const float* __restrict__ a1d, float* __restrict__ w1as,
    float* __restrict__ w1ad) {
  int idx = blockIdx.x * blockDim.x + threadIdx.x;
  if (idx >= 2 * F_IN * HEADS) return;
  int which = idx >= F_IN * HEADS;
  int r = which ? idx - F_IN * HEADS : idx;
  int k = r >> 3, h = r & 7;
  const float* a = which ? a1d : a1s;
  float s = 0.f;
  for (int c = 0; c < HID; ++c) s += W1[(size_t)k * WIDTH + h * HID + c] * a[h * HID + c];
  (which ? w1ad : w1as)[r] = s;
}

// al1[n,h] = sum_k x[n,k] * w1a[k,h]   (one wave per node)
__global__ __launch_bounds__(256) void al1_kernel(
    const float* __restrict__ x, const float* __restrict__ w1as,
    const float* __restrict__ w1ad, float* __restrict__ al_s,
    float* __restrict__ al_d) {
  int n = (blockIdx.x * blockDim.x + threadIdx.x) >> 6;
  int lane = threadIdx.x & 63;
  if (n >= NN) return;
  float xv = (lane < F_IN) ? x[(size_t)n * F_IN + lane] : 0.f;
  float ws[HEADS], wd[HEADS];
  #pragma unroll
  for (int h = 0; h < HEADS; ++h) {
    ws[h] = (lane < F_IN) ? w1as[lane * HEADS + h] : 0.f;
    wd[h] = (lane < F_IN) ? w1ad[lane * HEADS + h] : 0.f;
  }
  #pragma unroll
  for (int h = 0; h < HEADS; ++h) {
    float ss = xv * ws[h], sd = xv * wd[h];
    #pragma unroll
    for (int o = 32; o; o >>= 1) {
      ss += __shfl_xor(ss, o);
      sd += __shfl_xor(sd, o);
    }
    if (lane == 0) {
      al_s[n * HEADS + h] = ss;
      al_d[n * HEADS + h] = sd;
    }
  }
}

// ---------------- per-node attention logits (from h; H=1 layers) -----------
__global__ __launch_bounds__(256) void compute_al(
    const float* __restrict__ h, const float* __restrict__ a_src,
    const float* __restrict__ a_dst, float* __restrict__ al_s,
    float* __restrict__ al_d, int Nn, int H, int C) {
  int wave = (blockIdx.x * blockDim.x + threadIdx.x) >> 6;
  int lane = threadIdx.x & 63;
  if (wave >= Nn) return;
  const float* hr = h + (size_t)wave * H * C;
  for (int hd = 0; hd < H; ++hd) {
    float ss = 0.f, sd = 0.f;
    for (int c = lane; c < C; c += 64) {
      float v = hr[hd * C + c];
      ss += v * a_src[hd * C + c];
      sd += v * a_dst[hd * C + c];
    }
    #pragma unroll
    for (int o = 32; o; o >>= 1) {
      ss += __shfl_xor(ss, o);
      sd += __shfl_xor(sd, o);
    }
    if (lane == 0) {
      al_s[wave * H + hd] = ss;
      al_d[wave * H + hd] = sd;
    }
  }
}

// ---------------- CSR build (once; shared by all layers) --------------------
__global__ __launch_bounds__(256) void count_deg(
    const int* __restrict__ edst, int* __restrict__ deg) {
  int e = blockIdx.x * blockDim.x + threadIdx.x;
  if (e >= ETOT) return;
  int d = (e < ERAW) ? edst[e] : (e - ERAW);
  atomicAdd(&deg[d], 1);
}

__global__ __launch_bounds__(256) void scan_deg(
    const int* __restrict__ deg, int* __restrict__ rowptr) {
  __shared__ int part[256];
  const int t = threadIdx.x;
  const int CHUNK = (NN + 255) / 256;
  int lo = t * CHUNK, hi = min(lo + CHUNK, NN);
  int s = 0;
  for (int i = lo; i < hi; ++i) s += deg[i];
  part[t] = s;
  __syncthreads();
  for (int off = 1; off < 256; off <<= 1) {
    int v = (t >= off) ? part[t - off] : 0;
    __syncthreads();
    part[t] += v;
    __syncthreads();
  }
  int base = (t == 0) ? 0 : part[t - 1];
  for (int i = lo; i < hi; ++i) {
    rowptr[i] = base;
    base += deg[i];
  }
  if (t == 255) rowptr[NN] = part[255];
}

__global__ __launch_bounds__(256) void scatter_csr(
    const int* __restrict__ esrc, const int* __restrict__ edst,
    const int* __restrict__ rowptr, int* __restrict__ cnt,
    int* __restrict__ csrc) {
  int e = blockIdx.x * blockDim.x + threadIdx.x;
  if (e >= ETOT) return;
  int s, d;
  if (e < ERAW) { s = esrc[e]; d = edst[e]; }
  else          { s = e - ERAW; d = e - ERAW; }
  int pos = rowptr[d] + atomicAdd(&cnt[d], 1);
  csrc[pos] = s;
}

// ---- layer-1 fused: per-head softmax + aggregate x; bf16-split out --------
__global__ __launch_bounds__(256) void agg_x_sm(
    const int* __restrict__ rowptr, const int* __restrict__ csrc,
    const float* __restrict__ al_s, const float* __restrict__ al_d,
    const float* __restrict__ x, unsigned short* __restrict__ outHi,
    unsigned short* __restrict__ outLo) {
  const int w = threadIdx.x >> 6, lane = threadIdx.x & 63;
  const int d = blockIdx.x * 4 + w;
  if (d >= NN) return;
  const int r0 = rowptr[d], r1 = rowptr[d + 1];
  float ald[HEADS];
  #pragma unroll
  for (int hh = 0; hh < HEADS; ++hh) ald[hh] = al_d[d * HEADS + hh];

  // pass 1: per-head max (lane-strided)
  float mx[HEADS];
  #pragma unroll
  for (int hh = 0; hh < HEADS; ++hh) mx[hh] = -3.4e38f;
  for (int p = r0 + lane; p < r1; p += 64) {
    int s = csrc[p];
    #pragma unroll
    for (int hh = 0; hh < HEADS; ++hh) {
      float v = al_s[s * HEADS + hh] + ald[hh];
      v = (v > 0.f) ? v : 0.2f * v;
      mx[hh] = fmaxf(mx[hh], v);
    }
  }
  #pragma unroll
  for (int o = 32; o; o >>= 1)
    #pragma unroll
    for (int hh = 0; hh < HEADS; ++hh)
      mx[hh] = fmaxf(mx[hh], __shfl_xor(mx[hh], o));

  // pass 2: per-head z
  float zs[HEADS];
  #pragma unroll
  for (int hh = 0; hh < HEADS; ++hh) zs[hh] = 0.f;
  for (int p = r0 + lane; p < r1; p += 64) {
    int s = csrc[p];
    #pragma unroll
    for (int hh = 0; hh < HEADS; ++hh) {
      float v = al_s[s * HEADS + hh] + ald[hh];
      v = (v > 0.f) ? v : 0.2f * v;
      zs[hh] += __expf(v - mx[hh]);
    }
  }
  #pragma unroll
  for (int o = 32; o; o >>= 1)
    #pragma unroll
    for (int hh = 0; hh < HEADS; ++hh) zs[hh] += __shfl_xor(zs[hh], o);
  float iz[HEADS];
  #pragma unroll
  for (int hh = 0; hh < HEADS; ++hh) iz[hh] = 1.0f / (zs[hh] + 1e-16f);

  // per-lane head params (lane computes alpha for head lane&7)
  const int mh = lane & 7;
  const float m_my = sel8(mx, mh), iz_my = sel8(iz, mh), ald_my = sel8(ald, mh);

  // pass 3: aggregate (all lanes walk same edge)
  float acc[HEADS];
  #pragma unroll
  for (int hh = 0; hh < HEADS; ++hh) acc[hh] = 0.f;
  for (int p = r0; p < r1; ++p) {
    int s = csrc[p];
    float v = al_s[s * HEADS + mh] + ald_my;
    v = (v > 0.f) ? v : 0.2f * v;
    float a = __expf(v - m_my) * iz_my;
    float xv = (lane < F_IN) ? x[(size_t)s * F_IN + lane] : 0.f;
    #pragma unroll
    for (int hh = 0; hh < HEADS; ++hh) acc[hh] += __shfl(a, hh, 8) * xv;
  }
  #pragma unroll
  for (int hh = 0; hh < HEADS; ++hh) {
    float v = (lane < F_IN) ? acc[hh] : 0.f;
    unsigned short h2, l2;
    split_one(v, h2, l2);
    outHi[(size_t)d * WIDTH + hh * HID + lane] = h2;
    outLo[(size_t)d * WIDTH + hh * HID + lane] = l2;
  }
}

// ---- fused softmax + pull aggregation (H=1), wave per dst, 4x edge unroll -
template <int M, bool ELU, bool SPLIT>
__global__ __launch_bounds__(256) void pull_agg_sm(
    const int* __restrict__ rowptr, const int* __restrict__ csrc,
    const float* __restrict__ al_s, const float* __restrict__ al_d,
    const float* __restrict__ h, const float* __restrict__ bias,
    float* __restrict__ out, unsigned short* __restrict__ outHi,
    unsigned short* __restrict__ outLo) {
  constexpr int EPL = (M + 63) / 64;
  const int w = threadIdx.x >> 6;
  const int lane = threadIdx.x & 63;
  const int d = blockIdx.x * 4 + w;
  if (d >= NN) return;
  const int r0 = rowptr[d], r1 = rowptr[d + 1];
  const float ald = al_d[d];

  // pass 1: max
  float mx = -3.4e38f;
  for (int p = r0 + lane; p < r1; p += 64) {
    float v = al_s[csrc[p]] + ald;
    v = (v > 0.f) ? v : 0.2f * v;
    mx = fmaxf(mx, v);
  }
  #pragma unroll
  for (int o = 32; o; o >>= 1) mx = fmaxf(mx, __shfl_xor(mx, o));
  // pass 2: z
  float zs = 0.f;
  for (int p = r0 + lane; p < r1; p += 64) {
    float v = al_s[csrc[p]] + ald;
    v = (v > 0.f) ? v : 0.2f * v;
    zs += __expf(v - mx);
  }
  #pragma unroll
  for (int o = 32; o; o >>= 1) zs += __shfl_xor(zs, o);
  const float iz = 1.0f / (zs + 1e-16f);

  // pass 3: aggregate, 4x edge unroll for memory-level parallelism
  const int base = lane * EPL;
  float acc[EPL];
  #pragma unroll
  for (int j = 0; j < EPL; ++j) acc[j] = 0.f;

  int p = r0;
  for (; p + 4 <= r1; p += 4) {
    int s0 = csrc[p], s1 = csrc[p + 1], s2 = csrc[p + 2], s3 = csrc[p + 3];
    const float* h0 = h + (size_t)s0 * M + base;
    const float* h1 = h + (size_t)s1 * M + base;
    const float* h2 = h + (size_t)s2 * M + base;
    const float* h3 = h + (size_t)s3 * M + base;
    float t0[EPL], t1[EPL], t2[EPL], t3[EPL];
    #pragma unroll
    for (int j = 0; j < EPL; ++j) {
      if ((M % 64 == 0) || (base + j < M)) {
        t0[j] = h0[j]; t1[j] = h1[j]; t2[j] = h2[j]; t3[j] = h3[j];
      }
    }
    float v0 = al_s[s0] + ald; v0 = (v0 > 0.f) ? v0 : 0.2f * v0;
    float v1 = al_s[s1] + ald; v1 = (v1 > 0.f) ? v1 : 0.2f * v1;
    float v2 = al_s[s2] + ald; v2 = (v2 > 0.f) ? v2 : 0.2f * v2;
    float v3 = al_s[s3] + ald; v3 = (v3 > 0.f) ? v3 : 0.2f * v3;
    float a0 = __expf(v0 - mx) * iz;
    float a1 = __expf(v1 - mx) * iz;
    float a2 = __expf(v2 - mx) * iz;
    float a3 = __expf(v3 - mx) * iz;
    #pragma unroll
    for (int j = 0; j < EPL; ++j) {
      if ((M % 64 == 0) || (base + j < M)) {
        acc[j] += t0[j] * a0;
        acc[j] += t1[j] * a1;
        acc[j] += t2[j] * a2;
        acc[j] += t3[j] * a3;
      }
    }
  }
  for (; p < r1; ++p) {
    int s = csrc[p];
    float v = al_s[s] + ald;
    v = (v > 0.f) ? v : 0.2f * v;
    float a = __expf(v - mx) * iz;
    const float* hr = h + (size_t)s * M + base;
    #pragma unroll
    for (int j = 0; j < EPL; ++j) {
      if ((M % 64 == 0) || (base + j < M)) acc[j] += hr[j] * a;
    }
  }

  #pragma unroll
  for (int j = 0; j < EPL; ++j) {
    if ((M % 64 == 0) || (base + j < M)) {
      float v = acc[j] + bias[base + j];
      if (ELU) v = (v > 0.f) ? v : (__expf(v) - 1.0f);
      if (SPLIT) {
        unsigned short hh, ll;
        split_one(v, hh, ll);
        outHi[(size_t)d * M + base + j] = hh;
        outLo[(size_t)d * M + base + j] = ll;
      } else {
        out[(size_t)d * M + base + j] = v;
      }
    }
  }
}

extern "C" void kernel_launch(void* const* d_in, const int* in_sizes, int n_in,
                              void* d_out, int out_size, void* d_ws,
                              size_t ws_size, hipStream_t stream) {
  const float* x      = (const float*)d_in[0];
  const int*   ei     = (const int*)d_in[1];
  const float* W1     = (const float*)d_in[2];
  const float* a1_src = (const float*)d_in[3];
  const float* a1_dst = (const float*)d_in[4];
  const float* b1     = (const float*)d_in[5];
  const float* W2     = (const float*)d_in[6];
  const float* a2_src = (const float*)d_in[7];
  const float* a2_dst = (const float*)d_in[8];
  const float* b2     = (const float*)d_in[9];
  const float* W3     = (const float*)d_in[10];
  const float* a3_src = (const float*)d_in[11];
  const float* a3_dst = (const float*)d_in[12];
  const float* b3     = (const float*)d_in[13];
  float* out = (float*)d_out;

  const int* esrc = ei;
  const int* edst = ei + ERAW;

  // Workspace carve-up
  unsigned short* p1Hi  = (unsigned short*)d_ws;          // NN*WIDTH
  unsigned short* p1Lo  = p1Hi + (size_t)NN * WIDTH;
  unsigned short* p2Hi  = p1Lo + (size_t)NN * WIDTH;
  unsigned short* p2Lo  = p2Hi + (size_t)NN * WIDTH;
  unsigned short* w1hHi = p2Lo + (size_t)NN * WIDTH;      // 8*64*64
  unsigned short* w1hLo = w1hHi + (size_t)HEADS * HID * HID;
  unsigned short* w2tHi = w1hLo + (size_t)HEADS * HID * HID;  // 512*512
  unsigned short* w2tLo = w2tHi + (size_t)WIDTH * WIDTH;
  unsigned short* w3tHi = w2tLo + (size_t)WIDTH * WIDTH;  // 128*512
  unsigned short* w3tLo = w3tHi + (size_t)NCLS_P * WIDTH;
  float* bufA   = (float*)(w3tLo + (size_t)NCLS_P * WIDTH);  // NN*WIDTH (h)
  float* al_s   = bufA + (size_t)NN * WIDTH;
  float* al_d   = al_s + (size_t)NN * HEADS;
  float* w1as   = al_d + (size_t)NN * HEADS;              // 50*8
  float* w1ad   = w1as + F_IN * HEADS;
  int* deg      = (int*)(w1ad + F_IN * HEADS);
  int* rowptr   = deg + NN;
  int* cnt      = rowptr + NN + 4;
  int* csrc     = cnt + NN;                               // ETOT

  // ---- build CSR by destination (once) ----
  hipMemsetAsync(deg, 0, (size_t)NN * sizeof(int), stream);
  hipMemsetAsync(cnt, 0, (size_t)NN * sizeof(int), stream);
  const int eblk = (ETOT + 255) / 256;
  count_deg<<<eblk, 256, 0, stream>>>(edst, deg);
  scan_deg<<<1, 256, 0, stream>>>(deg, rowptr);
  scatter_csr<<<eblk, 256, 0, stream>>>(esrc, edst, rowptr, cnt, csrc);

  // ---- weight prep (once) ----
  build_w1h_t<<<(HEADS * HID * HID + 255) / 256, 256, 0, stream>>>(W1, w1hHi,
                                                                   w1hLo);
  transpose_split<<<dim3(WIDTH / 32, WIDTH / 32), 256, 0, stream>>>(
      W2, w2tHi, w2tLo, WIDTH, WIDTH, WIDTH);
  transpose_split<<<dim3(WIDTH / 32, NCLS_P / 32), 256, 0, stream>>>(
      W3, w3tHi, w3tLo, WIDTH, NCLS, NCLS_P);

  const int nwblk = (NN + 3) / 4;

  // ---- Layer 1 (aggregate-x-first; fused softmax+agg; per-head GEMM) ----
  {
    fold_w1a<<<(2 * F_IN * HEADS + 255) / 256, 256, 0, stream>>>(
        W1, a1_src, a1_dst, w1as, w1ad);
    al1_kernel<<<nwblk, 256, 0, stream>>>(x, w1as, w1ad, al_s, al_d);
    agg_x_sm<<<nwblk, 256, 0, stream>>>(rowptr, csrc, al_s, al_d, x, p1Hi,
                                        p1Lo);
    gemm_l1_heads<<<dim3((NN + 127) / 128, HEADS), 256, 0, stream>>>(
        p1Hi, p1Lo, w1hHi, w1hLo, p2Hi, p2Lo, b1);
  }
  // ---- Layer 2: h2 = x1 @ W2 -> bufA fp32; fused softmax-agg -> P1 split --
  {
    gemm_mfma_split<<<dim3(WIDTH / 128, (NN + 127) / 128), 256, 0, stream>>>(
        p2Hi, p2Lo, w2tHi, w2tLo, bufA, NN, WIDTH, WIDTH);
    compute_al<<<nwblk, 256, 0, stream>>>(bufA, a2_src, a2_dst, al_s, al_d,
                                          NN, 1, WIDTH);
    pull_agg_sm<WIDTH, true, true><<<nwblk, 256, 0, stream>>>(
        rowptr, csrc, al_s, al_d, bufA, b2, nullptr, p1Hi, p1Lo);
  }
  // ---- Layer 3: h3 = x2 @ W3 -> bufA; fused softmax-agg -> out (no ELU) ---
  {
    gemm_mfma_split<<<dim3(NCLS_P / 128, (NN + 127) / 128), 256, 0, stream>>>(
        p1Hi, p1Lo, w3tHi, w3tLo, bufA, NN, WIDTH, NCLS);
    compute_al<<<nwblk, 256, 0, stream>>>(bufA, a3_src, a3_dst, al_s, al_d,
                                          NN, 1, NCLS);
    pull_agg_sm<NCLS, false, false><<<nwblk, 256, 0, stream>>>(
        rowptr, csrc, al_s, al_d, bufA, b3, out, nullptr, nullptr);
  }
}

// Round 10
// 524.288 us; speedup vs baseline: 1.7128x; 1.0204x over previous
//
#include <hip/hip_runtime.h>
#include <hip/hip_bf16.h>

// Problem constants (match reference)
#define NN     20000
#define ERAW   320000
#define ETOT   (ERAW + NN)   // 340000 with self loops
#define F_IN   50
#define HID    64
#define HEADS  8
#define WIDTH  512           // HID*HEADS
#define NCLS   121
#define NCLS_P 128           // padded cols for layer-3 MFMA GEMM

typedef __attribute__((ext_vector_type(8))) __bf16 bf16x8;
typedef __attribute__((ext_vector_type(4))) float floatx4;

// ---------------- fp32 -> bf16 split helpers --------------------------------
__device__ __forceinline__ unsigned short f32_to_bf16_rn(float f) {
  unsigned u = __float_as_uint(f);
  unsigned r = u + 0x7fffu + ((u >> 16) & 1u);
  return (unsigned short)(r >> 16);
}
__device__ __forceinline__ void split_one(float f, unsigned short& h,
                                          unsigned short& l) {
  h = f32_to_bf16_rn(f);
  float fh = __uint_as_float(((unsigned)h) << 16);
  l = f32_to_bf16_rn(f - fh);
}

// W [K][M] fp32 -> Bt hi/lo [Mp][K] bf16 ushort (rows m>=M zero-padded)
__global__ __launch_bounds__(256) void transpose_split(
    const float* __restrict__ W, unsigned short* __restrict__ thi,
    unsigned short* __restrict__ tlo, int K, int M, int Mp) {
  __shared__ float t[32][33];
  int k0 = blockIdx.x * 32, m0 = blockIdx.y * 32;
  int tx = threadIdx.x & 31, ty = threadIdx.x >> 5;  // 32 x 8
  #pragma unroll
  for (int r = 0; r < 4; ++r) {
    int k = k0 + ty + r * 8, m = m0 + tx;
    float v = 0.f;
    if (k < K && m < M) v = W[(size_t)k * M + m];
    t[ty + r * 8][tx] = v;
  }
  __syncthreads();
  #pragma unroll
  for (int r = 0; r < 4; ++r) {
    int m = m0 + ty + r * 8, k = k0 + tx;
    if (m < Mp && k < K) {
      unsigned short h, l;
      split_one(t[tx][ty + r * 8], h, l);
      thi[(size_t)m * K + k] = h;
      tlo[(size_t)m * K + k] = l;
    }
  }
}

// Per-head W1 transposed split: w1h[hd][col(64)][k(64)], k>=50 zero.
__global__ __launch_bounds__(256) void build_w1h_t(
    const float* __restrict__ W1, unsigned short* __restrict__ thi,
    unsigned short* __restrict__ tlo) {
  int idx = blockIdx.x * blockDim.x + threadIdx.x;
  if (idx >= HEADS * HID * HID) return;
  int hd = idx >> 12, rem = idx & 4095;
  int col = rem >> 6, k = rem & 63;
  float v = (k < F_IN) ? W1[(size_t)k * WIDTH + hd * HID + col] : 0.f;
  unsigned short h, l;
  split_one(v, h, l);
  thi[idx] = h;
  tlo[idx] = l;
}

// ---- split-bf16 MFMA GEMM: C[N,M] = A[N,K] @ B[K,M] (B given as Bt[Mp][K]) -
__global__ __launch_bounds__(256) void gemm_mfma_split(
    const unsigned short* __restrict__ Ahi, const unsigned short* __restrict__ Alo,
    const unsigned short* __restrict__ Bthi, const unsigned short* __restrict__ Btlo,
    float* __restrict__ C, int N, int K, int M) {
  __shared__ unsigned short sAhi[4096], sAlo[4096], sBhi[4096], sBlo[4096];
  const int tid = threadIdx.x;
  const int wave = tid >> 6, lane = tid & 63;
  const int wr = wave >> 1, wc = wave & 1;
  const int r0 = blockIdx.y * 128;
  const int c0 = blockIdx.x * 128;
  const int lkg = lane >> 4;
  const int lmn = lane & 15;

  const int skg = tid & 3;
  const int srow = tid >> 2;
  int ra0 = r0 + srow;        if (ra0 > NN - 1) ra0 = NN - 1;
  int ra1 = r0 + srow + 64;   if (ra1 > NN - 1) ra1 = NN - 1;
  const unsigned short* gAhi0 = Ahi + (size_t)ra0 * K + skg * 8;
  const unsigned short* gAhi1 = Ahi + (size_t)ra1 * K + skg * 8;
  const unsigned short* gAlo0 = Alo + (size_t)ra0 * K + skg * 8;
  const unsigned short* gAlo1 = Alo + (size_t)ra1 * K + skg * 8;
  const unsigned short* gBhi0 = Bthi + (size_t)(c0 + srow) * K + skg * 8;
  const unsigned short* gBhi1 = Bthi + (size_t)(c0 + srow + 64) * K + skg * 8;
  const unsigned short* gBlo0 = Btlo + (size_t)(c0 + srow) * K + skg * 8;
  const unsigned short* gBlo1 = Btlo + (size_t)(c0 + srow + 64) * K + skg * 8;

  floatx4 acc[4][4] = {};

  uint4 a0, a1, a2, a3, b0, b1, b2, b3;
  auto gload = [&](int kk) {
    a0 = *(const uint4*)(gAhi0 + kk);
    a1 = *(const uint4*)(gAhi1 + kk);
    a2 = *(const uint4*)(gAlo0 + kk);
    a3 = *(const uint4*)(gAlo1 + kk);
    b0 = *(const uint4*)(gBhi0 + kk);
    b1 = *(const uint4*)(gBhi1 + kk);
    b2 = *(const uint4*)(gBlo0 + kk);
    b3 = *(const uint4*)(gBlo1 + kk);
  };
  gload(0);

  const int w0 = (skg * 128 + srow) * 8;
  const int w1 = (skg * 128 + srow + 64) * 8;

  for (int k0 = 0; k0 < K; k0 += 32) {
    __syncthreads();
    *(uint4*)(sAhi + w0) = a0;
    *(uint4*)(sAhi + w1) = a1;
    *(uint4*)(sAlo + w0) = a2;
    *(uint4*)(sAlo + w1) = a3;
    *(uint4*)(sBhi + w0) = b0;
    *(uint4*)(sBhi + w1) = b1;
    *(uint4*)(sBlo + w0) = b2;
    *(uint4*)(sBlo + w1) = b3;
    __syncthreads();
    if (k0 + 32 < K) gload(k0 + 32);

    bf16x8 fAhi[4], fAlo[4], fBhi[4], fBlo[4];
    #pragma unroll
    for (int mi = 0; mi < 4; ++mi) {
      int m = wr * 64 + mi * 16 + lmn;
      fAhi[mi] = *(const bf16x8*)(sAhi + (lkg * 128 + m) * 8);
      fAlo[mi] = *(const bf16x8*)(sAlo + (lkg * 128 + m) * 8);
    }
    #pragma unroll
    for (int ni = 0; ni < 4; ++ni) {
      int n = wc * 64 + ni * 16 + lmn;
      fBhi[ni] = *(const bf16x8*)(sBhi + (lkg * 128 + n) * 8);
      fBlo[ni] = *(const bf16x8*)(sBlo + (lkg * 128 + n) * 8);
    }
    #pragma unroll
    for (int mi = 0; mi < 4; ++mi)
      #pragma unroll
      for (int ni = 0; ni < 4; ++ni) {
        acc[mi][ni] = __builtin_amdgcn_mfma_f32_16x16x32_bf16(
            fAhi[mi], fBhi[ni], acc[mi][ni], 0, 0, 0);
        acc[mi][ni] = __builtin_amdgcn_mfma_f32_16x16x32_bf16(
            fAhi[mi], fBlo[ni], acc[mi][ni], 0, 0, 0);
        acc[mi][ni] = __builtin_amdgcn_mfma_f32_16x16x32_bf16(
            fAlo[mi], fBhi[ni], acc[mi][ni], 0, 0, 0);
      }
  }

  #pragma unroll
  for (int mi = 0; mi < 4; ++mi) {
    #pragma unroll
    for (int r = 0; r < 4; ++r) {
      int grow = r0 + wr * 64 + mi * 16 + (lane >> 4) * 4 + r;
      if (grow >= N) continue;
      #pragma unroll
      for (int ni = 0; ni < 4; ++ni) {
        int gcol = c0 + wc * 64 + ni * 16 + lmn;
        if (gcol < M) C[(size_t)grow * M + gcol] = acc[mi][ni][r];
      }
    }
  }
}

// ---- batched per-head L1 GEMM: C[n,hd*64+c] = elu(A[n,hd*64+:64]@W1h + b1) -
__global__ __launch_bounds__(256) void gemm_l1_heads(
    const unsigned short* __restrict__ Ahi, const unsigned short* __restrict__ Alo,
    const unsigned short* __restrict__ Bthi, const unsigned short* __restrict__ Btlo,
    unsigned short* __restrict__ outHi, unsigned short* __restrict__ outLo,
    const float* __restrict__ bias) {
  __shared__ unsigned short sAhi[8192], sAlo[8192], sBhi[4096], sBlo[4096];
  const int tid = threadIdx.x;
  const int wave = tid >> 6, lane = tid & 63;
  const int r0 = blockIdx.x * 128;
  const int hd = blockIdx.y;
  const int lkg = lane >> 4, lmn = lane & 15;

  #pragma unroll
  for (int t = 0; t < 4; ++t) {
    int cid = tid + t * 256;
    int row = cid >> 3, c = cid & 7;
    int gr = r0 + row; if (gr > NN - 1) gr = NN - 1;
    const size_t goff = (size_t)gr * WIDTH + hd * HID + c * 8;
    int loff = (((c >> 2) * 4 + (c & 3)) * 128 + row) * 8;
    *(uint4*)(sAhi + loff) = *(const uint4*)(Ahi + goff);
    *(uint4*)(sAlo + loff) = *(const uint4*)(Alo + goff);
  }
  #pragma unroll
  for (int t = 0; t < 2; ++t) {
    int cid = tid + t * 256;
    int col = cid >> 3, c = cid & 7;
    const size_t goff = (size_t)(hd * HID + col) * HID + c * 8;
    int loff = (((c >> 2) * 4 + (c & 3)) * 64 + col) * 8;
    *(uint4*)(sBhi + loff) = *(const uint4*)(Bthi + goff);
    *(uint4*)(sBlo + loff) = *(const uint4*)(Btlo + goff);
  }
  __syncthreads();

  floatx4 acc[2][4] = {};
  #pragma unroll
  for (int ks = 0; ks < 2; ++ks) {
    bf16x8 fAhi[2], fAlo[2], fBhi[4], fBlo[4];
    #pragma unroll
    for (int mi = 0; mi < 2; ++mi) {
      int m = wave * 32 + mi * 16 + lmn;
      int off = ((ks * 4 + lkg) * 128 + m) * 8;
      fAhi[mi] = *(const bf16x8*)(sAhi + off);
      fAlo[mi] = *(const bf16x8*)(sAlo + off);
    }
    #pragma unroll
    for (int ni = 0; ni < 4; ++ni) {
      int n = ni * 16 + lmn;
      int off = ((ks * 4 + lkg) * 64 + n) * 8;
      fBhi[ni] = *(const bf16x8*)(sBhi + off);
      fBlo[ni] = *(const bf16x8*)(sBlo + off);
    }
    #pragma unroll
    for (int mi = 0; mi < 2; ++mi)
      #pragma unroll
      for (int ni = 0; ni < 4; ++ni) {
        acc[mi][ni] = __builtin_amdgcn_mfma_f32_16x16x32_bf16(
            fAhi[mi], fBhi[ni], acc[mi][ni], 0, 0, 0);
        acc[mi][ni] = __builtin_amdgcn_mfma_f32_16x16x32_bf16(
            fAhi[mi], fBlo[ni], acc[mi][ni], 0, 0, 0);
        acc[mi][ni] = __builtin_amdgcn_mfma_f32_16x16x32_bf16(
            fAlo[mi], fBhi[ni], acc[mi][ni], 0, 0, 0);
      }
  }

  #pragma unroll
  for (int mi = 0; mi < 2; ++mi) {
    #pragma unroll
    for (int r = 0; r < 4; ++r) {
      int grow = r0 + wave * 32 + mi * 16 + (lane >> 4) * 4 + r;
      if (grow >= NN) continue;
      #pragma unroll
      for (int ni = 0; ni < 4; ++ni) {
        int gcol = hd * HID + ni * 16 + lmn;
        float v = acc[mi][ni][r] + bias[gcol];
        v = (v > 0.f) ? v : (__expf(v) - 1.0f);
        unsigned short hh, ll;
        split_one(v, hh, ll);
        outHi[(size_t)grow * WIDTH + gcol] = hh;
        outLo[(size_t)grow * WIDTH + gcol] = ll;
      }
    }
  }
}

// ---------------- layer-1 folded attention weights --------------------------
__global__ __launch_bounds__(256) void fold_w1a(
    const float* __restrict__ W1, const float* __restrict__ a1s,
    const float* __restrict__ a1d, float* __restrict__ w1as,
    float* __restrict__ w1ad) {
  int idx = blockIdx.x * blockDim.x + threadIdx.x;
  if (idx >= 2 * F_IN * HEADS) return;
  int which = idx >= F_IN * HEADS;
  int r = which ? idx - F_IN * HEADS : idx;
  int k = r >> 3, h = r & 7;
  const float* a = which ? a1d : a1s;
  float s = 0.f;
  for (int c = 0; c < HID; ++c) s += W1[(size_t)k * WIDTH + h * HID + c] * a[h * HID + c];
  (which ? w1ad : w1as)[r] = s;
}

// al1[n,h] = sum_k x[n,k] * w1a[k,h]   (one wave per node)
__global__ __launch_bounds__(256) void al1_kernel(
    const float* __restrict__ x, const float* __restrict__ w1as,
    const float* __restrict__ w1ad, float* __restrict__ al_s,
    float* __restrict__ al_d) {
  int n = (blockIdx.x * blockDim.x + threadIdx.x) >> 6;
  int lane = threadIdx.x & 63;
  if (n >= NN) return;
  float xv = (lane < F_IN) ? x[(size_t)n * F_IN + lane] : 0.f;
  float ws[HEADS], wd[HEADS];
  #pragma unroll
  for (int h = 0; h < HEADS; ++h) {
    ws[h] = (lane < F_IN) ? w1as[lane * HEADS + h] : 0.f;
    wd[h] = (lane < F_IN) ? w1ad[lane * HEADS + h] : 0.f;
  }
  #pragma unroll
  for (int h = 0; h < HEADS; ++h) {
    float ss = xv * ws[h], sd = xv * wd[h];
    #pragma unroll
    for (int o = 32; o; o >>= 1) {
      ss += __shfl_xor(ss, o);
      sd += __shfl_xor(sd, o);
    }
    if (lane == 0) {
      al_s[n * HEADS + h] = ss;
      al_d[n * HEADS + h] = sd;
    }
  }
}

// ---------------- per-node attention logits (from h; H=1 layers) -----------
__global__ __launch_bounds__(256) void compute_al(
    const float* __restrict__ h, const float* __restrict__ a_src,
    const float* __restrict__ a_dst, float* __restrict__ al_s,
    float* __restrict__ al_d, int Nn, int H, int C) {
  int wave = (blockIdx.x * blockDim.x + threadIdx.x) >> 6;
  int lane = threadIdx.x & 63;
  if (wave >= Nn) return;
  const float* hr = h + (size_t)wave * H * C;
  for (int hd = 0; hd < H; ++hd) {
    float ss = 0.f, sd = 0.f;
    for (int c = lane; c < C; c += 64) {
      float v = hr[hd * C + c];
      ss += v * a_src[hd * C + c];
      sd += v * a_dst[hd * C + c];
    }
    #pragma unroll
    for (int o = 32; o; o >>= 1) {
      ss += __shfl_xor(ss, o);
      sd += __shfl_xor(sd, o);
    }
    if (lane == 0) {
      al_s[wave * H + hd] = ss;
      al_d[wave * H + hd] = sd;
    }
  }
}

// ---------------- CSR build (once; shared by all layers) --------------------
__global__ __launch_bounds__(256) void count_deg(
    const int* __restrict__ edst, int* __restrict__ deg) {
  int e = blockIdx.x * blockDim.x + threadIdx.x;
  if (e >= ETOT) return;
  int d = (e < ERAW) ? edst[e] : (e - ERAW);
  atomicAdd(&deg[d], 1);
}

__global__ __launch_bounds__(256) void scan_deg(
    const int* __restrict__ deg, int* __restrict__ rowptr) {
  __shared__ int part[256];
  const int t = threadIdx.x;
  const int CHUNK = (NN + 255) / 256;
  int lo = t * CHUNK, hi = min(lo + CHUNK, NN);
  int s = 0;
  for (int i = lo; i < hi; ++i) s += deg[i];
  part[t] = s;
  __syncthreads();
  for (int off = 1; off < 256; off <<= 1) {
    int v = (t >= off) ? part[t - off] : 0;
    __syncthreads();
    part[t] += v;
    __syncthreads();
  }
  int base = (t == 0) ? 0 : part[t - 1];
  for (int i = lo; i < hi; ++i) {
    rowptr[i] = base;
    base += deg[i];
  }
  if (t == 255) rowptr[NN] = part[255];
}

__global__ __launch_bounds__(256) void scatter_csr(
    const int* __restrict__ esrc, const int* __restrict__ edst,
    const int* __restrict__ rowptr, int* __restrict__ cnt,
    int* __restrict__ csrc) {
  int e = blockIdx.x * blockDim.x + threadIdx.x;
  if (e >= ETOT) return;
  int s, d;
  if (e < ERAW) { s = esrc[e]; d = edst[e]; }
  else          { s = e - ERAW; d = e - ERAW; }
  int pos = rowptr[d] + atomicAdd(&cnt[d], 1);
  csrc[pos] = s;
}

// ---- layer-1 fused SINGLE-PASS softmax+aggregate (self-loop-logit shift) --
// alpha_e = exp(v_e - m)/z with m = lrelu(al_s[d]+al_d[d]) (a fixed per-dst
// shift -> mathematically identical softmax; self-loop guarantees z >= 1).
__global__ __launch_bounds__(256) void agg_x_sm(
    const int* __restrict__ rowptr, const int* __restrict__ csrc,
    const float* __restrict__ al_s, const float* __restrict__ al_d,
    const float* __restrict__ x, unsigned short* __restrict__ outHi,
    unsigned short* __restrict__ outLo) {
  const int w = threadIdx.x >> 6, lane = threadIdx.x & 63;
  const int d = blockIdx.x * 4 + w;
  if (d >= NN) return;
  const int r0 = rowptr[d], r1 = rowptr[d + 1];
  const int mh = lane & 7;  // this lane computes alpha for head mh
  const float ald_my = al_d[d * HEADS + mh];
  float m_my = al_s[d * HEADS + mh] + ald_my;
  m_my = (m_my > 0.f) ? m_my : 0.2f * m_my;

  float z_my = 0.f;
  float acc[HEADS];
  #pragma unroll
  for (int hh = 0; hh < HEADS; ++hh) acc[hh] = 0.f;
  for (int p = r0; p < r1; ++p) {
    int s = csrc[p];
    float v = al_s[s * HEADS + mh] + ald_my;
    v = (v > 0.f) ? v : 0.2f * v;
    float a = __expf(v - m_my);
    z_my += a;                      // full z for head mh (all lanes walk all edges)
    float xv = (lane < F_IN) ? x[(size_t)s * F_IN + lane] : 0.f;
    #pragma unroll
    for (int hh = 0; hh < HEADS; ++hh) acc[hh] += __shfl(a, hh, 8) * xv;
  }
  #pragma unroll
  for (int hh = 0; hh < HEADS; ++hh) {
    float zh = __shfl(z_my, hh, 8);       // lane hh in group holds z of head hh
    float v = (lane < F_IN) ? acc[hh] / (zh + 1e-16f) : 0.f;
    unsigned short h2, l2;
    split_one(v, h2, l2);
    outHi[(size_t)d * WIDTH + hh * HID + lane] = h2;
    outLo[(size_t)d * WIDTH + hh * HID + lane] = l2;
  }
}

// ---- fused SINGLE-PASS softmax + pull aggregation (H=1), wave per dst -----
template <int M, bool ELU, bool SPLIT>
__global__ __launch_bounds__(256) void pull_agg_sm(
    const int* __restrict__ rowptr, const int* __restrict__ csrc,
    const float* __restrict__ al_s, const float* __restrict__ al_d,
    const float* __restrict__ h, const float* __restrict__ bias,
    float* __restrict__ out, unsigned short* __restrict__ outHi,
    unsigned short* __restrict__ outLo) {
  constexpr int EPL = (M + 63) / 64;
  const int w = threadIdx.x >> 6;
  const int lane = threadIdx.x & 63;
  const int d = blockIdx.x * 4 + w;
  if (d >= NN) return;
  const int r0 = rowptr[d], r1 = rowptr[d + 1];
  const float ald = al_d[d];
  float m = al_s[d] + ald;                 // self-loop logit as softmax shift
  m = (m > 0.f) ? m : 0.2f * m;

  const int base = lane * EPL;
  float acc[EPL];
  #pragma unroll
  for (int j = 0; j < EPL; ++j) acc[j] = 0.f;
  float z = 0.f;                           // identical across lanes

  for (int p = r0; p < r1; ++p) {
    int s = csrc[p];
    float v = al_s[s] + ald;               // broadcast load
    v = (v > 0.f) ? v : 0.2f * v;
    float a = __expf(v - m);
    z += a;
    const float* hr = h + (size_t)s * M + base;
    #pragma unroll
    for (int j = 0; j < EPL; ++j) {
      if ((M % 64 == 0) || (base + j < M)) acc[j] += hr[j] * a;
    }
  }
  const float iz = 1.0f / (z + 1e-16f);

  #pragma unroll
  for (int j = 0; j < EPL; ++j) {
    if ((M % 64 == 0) || (base + j < M)) {
      float v = acc[j] * iz + bias[base + j];
      if (ELU) v = (v > 0.f) ? v : (__expf(v) - 1.0f);
      if (SPLIT) {
        unsigned short hh, ll;
        split_one(v, hh, ll);
        outHi[(size_t)d * M + base + j] = hh;
        outLo[(size_t)d * M + base + j] = ll;
      } else {
        out[(size_t)d * M + base + j] = v;
      }
    }
  }
}

extern "C" void kernel_launch(void* const* d_in, const int* in_sizes, int n_in,
                              void* d_out, int out_size, void* d_ws,
                              size_t ws_size, hipStream_t stream) {
  const float* x      = (const float*)d_in[0];
  const int*   ei     = (const int*)d_in[1];
  const float* W1     = (const float*)d_in[2];
  const float* a1_src = (const float*)d_in[3];
  const float* a1_dst = (const float*)d_in[4];
  const float* b1     = (const float*)d_in[5];
  const float* W2     = (const float*)d_in[6];
  const float* a2_src = (const float*)d_in[7];
  const float* a2_dst = (const float*)d_in[8];
  const float* b2     = (const float*)d_in[9];
  const float* W3     = (const float*)d_in[10];
  const float* a3_src = (const float*)d_in[11];
  const float* a3_dst = (const float*)d_in[12];
  const float* b3     = (const float*)d_in[13];
  float* out = (float*)d_out;

  const int* esrc = ei;
  const int* edst = ei + ERAW;

  // Workspace carve-up
  unsigned short* p1Hi  = (unsigned short*)d_ws;          // NN*WIDTH
  unsigned short* p1Lo  = p1Hi + (size_t)NN * WIDTH;
  unsigned short* p2Hi  = p1Lo + (size_t)NN * WIDTH;
  unsigned short* p2Lo  = p2Hi + (size_t)NN * WIDTH;
  unsigned short* w1hHi = p2Lo + (size_t)NN * WIDTH;      // 8*64*64
  unsigned short* w1hLo = w1hHi + (size_t)HEADS * HID * HID;
  unsigned short* w2tHi = w1hLo + (size_t)HEADS * HID * HID;  // 512*512
  unsigned short* w2tLo = w2tHi + (size_t)WIDTH * WIDTH;
  unsigned short* w3tHi = w2tLo + (size_t)WIDTH * WIDTH;  // 128*512
  unsigned short* w3tLo = w3tHi + (size_t)NCLS_P * WIDTH;
  float* bufA   = (float*)(w3tLo + (size_t)NCLS_P * WIDTH);  // NN*WIDTH (h)
  float* al_s   = bufA + (size_t)NN * WIDTH;
  float* al_d   = al_s + (size_t)NN * HEADS;
  float* w1as   = al_d + (size_t)NN * HEADS;              // 50*8
  float* w1ad   = w1as + F_IN * HEADS;
  int* deg      = (int*)(w1ad + F_IN * HEADS);
  int* rowptr   = deg + NN;
  int* cnt      = rowptr + NN + 4;
  int* csrc     = cnt + NN;                               // ETOT

  // ---- build CSR by destination (once) ----
  hipMemsetAsync(deg, 0, (size_t)NN * sizeof(int), stream);
  hipMemsetAsync(cnt, 0, (size_t)NN * sizeof(int), stream);
  const int eblk = (ETOT + 255) / 256;
  count_deg<<<eblk, 256, 0, stream>>>(edst, deg);
  scan_deg<<<1, 256, 0, stream>>>(deg, rowptr);
  scatter_csr<<<eblk, 256, 0, stream>>>(esrc, edst, rowptr, cnt, csrc);

  // ---- weight prep (once) ----
  build_w1h_t<<<(HEADS * HID * HID + 255) / 256, 256, 0, stream>>>(W1, w1hHi,
                                                                   w1hLo);
  transpose_split<<<dim3(WIDTH / 32, WIDTH / 32), 256, 0, stream>>>(
      W2, w2tHi, w2tLo, WIDTH, WIDTH, WIDTH);
  transpose_split<<<dim3(WIDTH / 32, NCLS_P / 32), 256, 0, stream>>>(
      W3, w3tHi, w3tLo, WIDTH, NCLS, NCLS_P);

  const int nwblk = (NN + 3) / 4;

  // ---- Layer 1 (aggregate-x-first; single-pass softmax+agg; head GEMM) ----
  {
    fold_w1a<<<(2 * F_IN * HEADS + 255) / 256, 256, 0, stream>>>(
        W1, a1_src, a1_dst, w1as, w1ad);
    al1_kernel<<<nwblk, 256, 0, stream>>>(x, w1as, w1ad, al_s, al_d);
    agg_x_sm<<<nwblk, 256, 0, stream>>>(rowptr, csrc, al_s, al_d, x, p1Hi,
                                        p1Lo);
    gemm_l1_heads<<<dim3((NN + 127) / 128, HEADS), 256, 0, stream>>>(
        p1Hi, p1Lo, w1hHi, w1hLo, p2Hi, p2Lo, b1);
  }
  // ---- Layer 2: h2 = x1 @ W2 -> bufA fp32; fused softmax-agg -> P1 split --
  {
    gemm_mfma_split<<<dim3(WIDTH / 128, (NN + 127) / 128), 256, 0, stream>>>(
        p2Hi, p2Lo, w2tHi, w2tLo, bufA, NN, WIDTH, WIDTH);
    compute_al<<<nwblk, 256, 0, stream>>>(bufA, a2_src, a2_dst, al_s, al_d,
                                          NN, 1, WIDTH);
    pull_agg_sm<WIDTH, true, true><<<nwblk, 256, 0, stream>>>(
        rowptr, csrc, al_s, al_d, bufA, b2, nullptr, p1Hi, p1Lo);
  }
  // ---- Layer 3: h3 = x2 @ W3 -> bufA; fused softmax-agg -> out (no ELU) ---
  {
    gemm_mfma_split<<<dim3(NCLS_P / 128, (NN + 127) / 128), 256, 0, stream>>>(
        p1Hi, p1Lo, w3tHi, w3tLo, bufA, NN, WIDTH, NCLS);
    compute_al<<<nwblk, 256, 0, stream>>>(bufA, a3_src, a3_dst, al_s, al_d,
                                          NN, 1, NCLS);
    pull_agg_sm<NCLS, false, false><<<nwblk, 256, 0, stream>>>(
        rowptr, csrc, al_s, al_d, bufA, b3, out, nullptr, nullptr);
  }
}

// Round 11
// 482.371 us; speedup vs baseline: 1.8616x; 1.0869x over previous
//
#include <hip/hip_runtime.h>
#include <hip/hip_bf16.h>
#include <hip/hip_fp16.h>

// Problem constants (match reference)
#define NN     20000
#define ERAW   320000
#define ETOT   (ERAW + NN)   // 340000 with self loops
#define F_IN   50
#define HID    64
#define HEADS  8
#define WIDTH  512           // HID*HEADS
#define NCLS   121
#define NCLS_P 128           // padded cols for layer-3 MFMA GEMM

typedef __attribute__((ext_vector_type(8))) __bf16 bf16x8;
typedef __attribute__((ext_vector_type(4))) float floatx4;

// ---------------- fp32 -> bf16 split helpers --------------------------------
__device__ __forceinline__ unsigned short f32_to_bf16_rn(float f) {
  unsigned u = __float_as_uint(f);
  unsigned r = u + 0x7fffu + ((u >> 16) & 1u);
  return (unsigned short)(r >> 16);
}
__device__ __forceinline__ void split_one(float f, unsigned short& h,
                                          unsigned short& l) {
  h = f32_to_bf16_rn(f);
  float fh = __uint_as_float(((unsigned)h) << 16);
  l = f32_to_bf16_rn(f - fh);
}

__device__ __forceinline__ float2 u2f2(unsigned u) {
  __half2 hv = *reinterpret_cast<__half2*>(&u);
  return __half22float2(hv);
}

// W [K][M] fp32 -> Bt hi/lo [Mp][K] bf16 ushort (rows m>=M zero-padded)
__global__ __launch_bounds__(256) void transpose_split(
    const float* __restrict__ W, unsigned short* __restrict__ thi,
    unsigned short* __restrict__ tlo, int K, int M, int Mp) {
  __shared__ float t[32][33];
  int k0 = blockIdx.x * 32, m0 = blockIdx.y * 32;
  int tx = threadIdx.x & 31, ty = threadIdx.x >> 5;  // 32 x 8
  #pragma unroll
  for (int r = 0; r < 4; ++r) {
    int k = k0 + ty + r * 8, m = m0 + tx;
    float v = 0.f;
    if (k < K && m < M) v = W[(size_t)k * M + m];
    t[ty + r * 8][tx] = v;
  }
  __syncthreads();
  #pragma unroll
  for (int r = 0; r < 4; ++r) {
    int m = m0 + ty + r * 8, k = k0 + tx;
    if (m < Mp && k < K) {
      unsigned short h, l;
      split_one(t[tx][ty + r * 8], h, l);
      thi[(size_t)m * K + k] = h;
      tlo[(size_t)m * K + k] = l;
    }
  }
}

// Per-head W1 transposed split: w1h[hd][col(64)][k(64)], k>=50 zero.
__global__ __launch_bounds__(256) void build_w1h_t(
    const float* __restrict__ W1, unsigned short* __restrict__ thi,
    unsigned short* __restrict__ tlo) {
  int idx = blockIdx.x * blockDim.x + threadIdx.x;
  if (idx >= HEADS * HID * HID) return;
  int hd = idx >> 12, rem = idx & 4095;
  int col = rem >> 6, k = rem & 63;
  float v = (k < F_IN) ? W1[(size_t)k * WIDTH + hd * HID + col] : 0.f;
  unsigned short h, l;
  split_one(v, h, l);
  thi[idx] = h;
  tlo[idx] = l;
}

// ---- split-bf16 MFMA GEMM: C[N,M] = A[N,K] @ B[K,M] (B given as Bt[Mp][K]) -
// Writes fp32 C (for compute_al) AND fp16 C16 (for the gather kernels).
__global__ __launch_bounds__(256) void gemm_mfma_split(
    const unsigned short* __restrict__ Ahi, const unsigned short* __restrict__ Alo,
    const unsigned short* __restrict__ Bthi, const unsigned short* __restrict__ Btlo,
    float* __restrict__ C, __half* __restrict__ C16, int N, int K, int M) {
  __shared__ unsigned short sAhi[4096], sAlo[4096], sBhi[4096], sBlo[4096];
  const int tid = threadIdx.x;
  const int wave = tid >> 6, lane = tid & 63;
  const int wr = wave >> 1, wc = wave & 1;
  const int r0 = blockIdx.y * 128;
  const int c0 = blockIdx.x * 128;
  const int lkg = lane >> 4;
  const int lmn = lane & 15;

  const int skg = tid & 3;
  const int srow = tid >> 2;
  int ra0 = r0 + srow;        if (ra0 > NN - 1) ra0 = NN - 1;
  int ra1 = r0 + srow + 64;   if (ra1 > NN - 1) ra1 = NN - 1;
  const unsigned short* gAhi0 = Ahi + (size_t)ra0 * K + skg * 8;
  const unsigned short* gAhi1 = Ahi + (size_t)ra1 * K + skg * 8;
  const unsigned short* gAlo0 = Alo + (size_t)ra0 * K + skg * 8;
  const unsigned short* gAlo1 = Alo + (size_t)ra1 * K + skg * 8;
  const unsigned short* gBhi0 = Bthi + (size_t)(c0 + srow) * K + skg * 8;
  const unsigned short* gBhi1 = Bthi + (size_t)(c0 + srow + 64) * K + skg * 8;
  const unsigned short* gBlo0 = Btlo + (size_t)(c0 + srow) * K + skg * 8;
  const unsigned short* gBlo1 = Btlo + (size_t)(c0 + srow + 64) * K + skg * 8;

  floatx4 acc[4][4] = {};

  uint4 a0, a1, a2, a3, b0, b1, b2, b3;
  auto gload = [&](int kk) {
    a0 = *(const uint4*)(gAhi0 + kk);
    a1 = *(const uint4*)(gAhi1 + kk);
    a2 = *(const uint4*)(gAlo0 + kk);
    a3 = *(const uint4*)(gAlo1 + kk);
    b0 = *(const uint4*)(gBhi0 + kk);
    b1 = *(const uint4*)(gBhi1 + kk);
    b2 = *(const uint4*)(gBlo0 + kk);
    b3 = *(const uint4*)(gBlo1 + kk);
  };
  gload(0);

  const int w0 = (skg * 128 + srow) * 8;
  const int w1 = (skg * 128 + srow + 64) * 8;

  for (int k0 = 0; k0 < K; k0 += 32) {
    __syncthreads();
    *(uint4*)(sAhi + w0) = a0;
    *(uint4*)(sAhi + w1) = a1;
    *(uint4*)(sAlo + w0) = a2;
    *(uint4*)(sAlo + w1) = a3;
    *(uint4*)(sBhi + w0) = b0;
    *(uint4*)(sBhi + w1) = b1;
    *(uint4*)(sBlo + w0) = b2;
    *(uint4*)(sBlo + w1) = b3;
    __syncthreads();
    if (k0 + 32 < K) gload(k0 + 32);

    bf16x8 fAhi[4], fAlo[4], fBhi[4], fBlo[4];
    #pragma unroll
    for (int mi = 0; mi < 4; ++mi) {
      int m = wr * 64 + mi * 16 + lmn;
      fAhi[mi] = *(const bf16x8*)(sAhi + (lkg * 128 + m) * 8);
      fAlo[mi] = *(const bf16x8*)(sAlo + (lkg * 128 + m) * 8);
    }
    #pragma unroll
    for (int ni = 0; ni < 4; ++ni) {
      int n = wc * 64 + ni * 16 + lmn;
      fBhi[ni] = *(const bf16x8*)(sBhi + (lkg * 128 + n) * 8);
      fBlo[ni] = *(const bf16x8*)(sBlo + (lkg * 128 + n) * 8);
    }
    #pragma unroll
    for (int mi = 0; mi < 4; ++mi)
      #pragma unroll
      for (int ni = 0; ni < 4; ++ni) {
        acc[mi][ni] = __builtin_amdgcn_mfma_f32_16x16x32_bf16(
            fAhi[mi], fBhi[ni], acc[mi][ni], 0, 0, 0);
        acc[mi][ni] = __builtin_amdgcn_mfma_f32_16x16x32_bf16(
            fAhi[mi], fBlo[ni], acc[mi][ni], 0, 0, 0);
        acc[mi][ni] = __builtin_amdgcn_mfma_f32_16x16x32_bf16(
            fAlo[mi], fBhi[ni], acc[mi][ni], 0, 0, 0);
      }
  }

  #pragma unroll
  for (int mi = 0; mi < 4; ++mi) {
    #pragma unroll
    for (int r = 0; r < 4; ++r) {
      int grow = r0 + wr * 64 + mi * 16 + (lane >> 4) * 4 + r;
      if (grow >= N) continue;
      #pragma unroll
      for (int ni = 0; ni < 4; ++ni) {
        int gcol = c0 + wc * 64 + ni * 16 + lmn;
        if (gcol < M) {
          float v = acc[mi][ni][r];
          C[(size_t)grow * M + gcol] = v;
          C16[(size_t)grow * M + gcol] = __float2half(v);
        }
      }
    }
  }
}

// ---- batched per-head L1 GEMM: C[n,hd*64+c] = elu(A[n,hd*64+:64]@W1h + b1) -
__global__ __launch_bounds__(256) void gemm_l1_heads(
    const unsigned short* __restrict__ Ahi, const unsigned short* __restrict__ Alo,
    const unsigned short* __restrict__ Bthi, const unsigned short* __restrict__ Btlo,
    unsigned short* __restrict__ outHi, unsigned short* __restrict__ outLo,
    const float* __restrict__ bias) {
  __shared__ unsigned short sAhi[8192], sAlo[8192], sBhi[4096], sBlo[4096];
  const int tid = threadIdx.x;
  const int wave = tid >> 6, lane = tid & 63;
  const int r0 = blockIdx.x * 128;
  const int hd = blockIdx.y;
  const int lkg = lane >> 4, lmn = lane & 15;

  #pragma unroll
  for (int t = 0; t < 4; ++t) {
    int cid = tid + t * 256;
    int row = cid >> 3, c = cid & 7;
    int gr = r0 + row; if (gr > NN - 1) gr = NN - 1;
    const size_t goff = (size_t)gr * WIDTH + hd * HID + c * 8;
    int loff = (((c >> 2) * 4 + (c & 3)) * 128 + row) * 8;
    *(uint4*)(sAhi + loff) = *(const uint4*)(Ahi + goff);
    *(uint4*)(sAlo + loff) = *(const uint4*)(Alo + goff);
  }
  #pragma unroll
  for (int t = 0; t < 2; ++t) {
    int cid = tid + t * 256;
    int col = cid >> 3, c = cid & 7;
    const size_t goff = (size_t)(hd * HID + col) * HID + c * 8;
    int loff = (((c >> 2) * 4 + (c & 3)) * 64 + col) * 8;
    *(uint4*)(sBhi + loff) = *(const uint4*)(Bthi + goff);
    *(uint4*)(sBlo + loff) = *(const uint4*)(Btlo + goff);
  }
  __syncthreads();

  floatx4 acc[2][4] = {};
  #pragma unroll
  for (int ks = 0; ks < 2; ++ks) {
    bf16x8 fAhi[2], fAlo[2], fBhi[4], fBlo[4];
    #pragma unroll
    for (int mi = 0; mi < 2; ++mi) {
      int m = wave * 32 + mi * 16 + lmn;
      int off = ((ks * 4 + lkg) * 128 + m) * 8;
      fAhi[mi] = *(const bf16x8*)(sAhi + off);
      fAlo[mi] = *(const bf16x8*)(sAlo + off);
    }
    #pragma unroll
    for (int ni = 0; ni < 4; ++ni) {
      int n = ni * 16 + lmn;
      int off = ((ks * 4 + lkg) * 64 + n) * 8;
      fBhi[ni] = *(const bf16x8*)(sBhi + off);
      fBlo[ni] = *(const bf16x8*)(sBlo + off);
    }
    #pragma unroll
    for (int mi = 0; mi < 2; ++mi)
      #pragma unroll
      for (int ni = 0; ni < 4; ++ni) {
        acc[mi][ni] = __builtin_amdgcn_mfma_f32_16x16x32_bf16(
            fAhi[mi], fBhi[ni], acc[mi][ni], 0, 0, 0);
        acc[mi][ni] = __builtin_amdgcn_mfma_f32_16x16x32_bf16(
            fAhi[mi], fBlo[ni], acc[mi][ni], 0, 0, 0);
        acc[mi][ni] = __builtin_amdgcn_mfma_f32_16x16x32_bf16(
            fAlo[mi], fBhi[ni], acc[mi][ni], 0, 0, 0);
      }
  }

  #pragma unroll
  for (int mi = 0; mi < 2; ++mi) {
    #pragma unroll
    for (int r = 0; r < 4; ++r) {
      int grow = r0 + wave * 32 + mi * 16 + (lane >> 4) * 4 + r;
      if (grow >= NN) continue;
      #pragma unroll
      for (int ni = 0; ni < 4; ++ni) {
        int gcol = hd * HID + ni * 16 + lmn;
        float v = acc[mi][ni][r] + bias[gcol];
        v = (v > 0.f) ? v : (__expf(v) - 1.0f);
        unsigned short hh, ll;
        split_one(v, hh, ll);
        outHi[(size_t)grow * WIDTH + gcol] = hh;
        outLo[(size_t)grow * WIDTH + gcol] = ll;
      }
    }
  }
}

// ---------------- layer-1 folded attention weights --------------------------
__global__ __launch_bounds__(256) void fold_w1a(
    const float* __restrict__ W1, const float* __restrict__ a1s,
    const float* __restrict__ a1d, float* __restrict__ w1as,
    float* __restrict__ w1ad) {
  int idx = blockIdx.x * blockDim.x + threadIdx.x;
  if (idx >= 2 * F_IN * HEADS) return;
  int which = idx >= F_IN * HEADS;
  int r = which ? idx - F_IN * HEADS : idx;
  int k = r >> 3, h = r & 7;
  const float* a = which ? a1d : a1s;
  float s = 0.f;
  for (int c = 0; c < HID; ++c) s += W1[(size_t)k * WIDTH + h * HID + c] * a[h * HID + c];
  (which ? w1ad : w1as)[r] = s;
}

// al1[n,h] = sum_k x[n,k] * w1a[k,h]   (one wave per node)
__global__ __launch_bounds__(256) void al1_kernel(
    const float* __restrict__ x, const float* __restrict__ w1as,
    const float* __restrict__ w1ad, float* __restrict__ al_s,
    float* __restrict__ al_d) {
  int n = (blockIdx.x * blockDim.x + threadIdx.x) >> 6;
  int lane = threadIdx.x & 63;
  if (n >= NN) return;
  float xv = (lane < F_IN) ? x[(size_t)n * F_IN + lane] : 0.f;
  float ws[HEADS], wd[HEADS];
  #pragma unroll
  for (int h = 0; h < HEADS; ++h) {
    ws[h] = (lane < F_IN) ? w1as[lane * HEADS + h] : 0.f;
    wd[h] = (lane < F_IN) ? w1ad[lane * HEADS + h] : 0.f;
  }
  #pragma unroll
  for (int h = 0; h < HEADS; ++h) {
    float ss = xv * ws[h], sd = xv * wd[h];
    #pragma unroll
    for (int o = 32; o; o >>= 1) {
      ss += __shfl_xor(ss, o);
      sd += __shfl_xor(sd, o);
    }
    if (lane == 0) {
      al_s[n * HEADS + h] = ss;
      al_d[n * HEADS + h] = sd;
    }
  }
}

// ---------------- per-node attention logits (from h; H=1 layers) -----------
__global__ __launch_bounds__(256) void compute_al(
    const float* __restrict__ h, const float* __restrict__ a_src,
    const float* __restrict__ a_dst, float* __restrict__ al_s,
    float* __restrict__ al_d, int Nn, int H, int C) {
  int wave = (blockIdx.x * blockDim.x + threadIdx.x) >> 6;
  int lane = threadIdx.x & 63;
  if (wave >= Nn) return;
  const float* hr = h + (size_t)wave * H * C;
  for (int hd = 0; hd < H; ++hd) {
    float ss = 0.f, sd = 0.f;
    for (int c = lane; c < C; c += 64) {
      float v = hr[hd * C + c];
      ss += v * a_src[hd * C + c];
      sd += v * a_dst[hd * C + c];
    }
    #pragma unroll
    for (int o = 32; o; o >>= 1) {
      ss += __shfl_xor(ss, o);
      sd += __shfl_xor(sd, o);
    }
    if (lane == 0) {
      al_s[wave * H + hd] = ss;
      al_d[wave * H + hd] = sd;
    }
  }
}

// ---------------- CSR build (once; shared by all layers) --------------------
__global__ __launch_bounds__(256) void count_deg(
    const int* __restrict__ edst, int* __restrict__ deg) {
  int e = blockIdx.x * blockDim.x + threadIdx.x;
  if (e >= ETOT) return;
  int d = (e < ERAW) ? edst[e] : (e - ERAW);
  atomicAdd(&deg[d], 1);
}

__global__ __launch_bounds__(256) void scan_deg(
    const int* __restrict__ deg, int* __restrict__ rowptr) {
  __shared__ int part[256];
  const int t = threadIdx.x;
  const int CHUNK = (NN + 255) / 256;
  int lo = t * CHUNK, hi = min(lo + CHUNK, NN);
  int s = 0;
  for (int i = lo; i < hi; ++i) s += deg[i];
  part[t] = s;
  __syncthreads();
  for (int off = 1; off < 256; off <<= 1) {
    int v = (t >= off) ? part[t - off] : 0;
    __syncthreads();
    part[t] += v;
    __syncthreads();
  }
  int base = (t == 0) ? 0 : part[t - 1];
  for (int i = lo; i < hi; ++i) {
    rowptr[i] = base;
    base += deg[i];
  }
  if (t == 255) rowptr[NN] = part[255];
}

__global__ __launch_bounds__(256) void scatter_csr(
    const int* __restrict__ esrc, const int* __restrict__ edst,
    const int* __restrict__ rowptr, int* __restrict__ cnt,
    int* __restrict__ csrc) {
  int e = blockIdx.x * blockDim.x + threadIdx.x;
  if (e >= ETOT) return;
  int s, d;
  if (e < ERAW) { s = esrc[e]; d = edst[e]; }
  else          { s = e - ERAW; d = e - ERAW; }
  int pos = rowptr[d] + atomicAdd(&cnt[d], 1);
  csrc[pos] = s;
}

// ---- layer-1 fused SINGLE-PASS softmax+aggregate (self-loop-logit shift) --
__global__ __launch_bounds__(256) void agg_x_sm(
    const int* __restrict__ rowptr, const int* __restrict__ csrc,
    const float* __restrict__ al_s, const float* __restrict__ al_d,
    const float* __restrict__ x, unsigned short* __restrict__ outHi,
    unsigned short* __restrict__ outLo) {
  const int w = threadIdx.x >> 6, lane = threadIdx.x & 63;
  const int d = blockIdx.x * 4 + w;
  if (d >= NN) return;
  const int r0 = rowptr[d], r1 = rowptr[d + 1];
  const int mh = lane & 7;  // this lane computes alpha for head mh
  const float ald_my = al_d[d * HEADS + mh];
  float m_my = al_s[d * HEADS + mh] + ald_my;
  m_my = (m_my > 0.f) ? m_my : 0.2f * m_my;

  float z_my = 0.f;
  float acc[HEADS];
  #pragma unroll
  for (int hh = 0; hh < HEADS; ++hh) acc[hh] = 0.f;
  for (int p = r0; p < r1; ++p) {
    int s = csrc[p];
    float v = al_s[s * HEADS + mh] + ald_my;
    v = (v > 0.f) ? v : 0.2f * v;
    float a = __expf(v - m_my);
    z_my += a;
    float xv = (lane < F_IN) ? x[(size_t)s * F_IN + lane] : 0.f;
    #pragma unroll
    for (int hh = 0; hh < HEADS; ++hh) acc[hh] += __shfl(a, hh, 8) * xv;
  }
  #pragma unroll
  for (int hh = 0; hh < HEADS; ++hh) {
    float zh = __shfl(z_my, hh, 8);
    float v = (lane < F_IN) ? acc[hh] / (zh + 1e-16f) : 0.f;
    unsigned short h2, l2;
    split_one(v, h2, l2);
    outHi[(size_t)d * WIDTH + hh * HID + lane] = h2;
    outLo[(size_t)d * WIDTH + hh * HID + lane] = l2;
  }
}

// ---- fused SINGLE-PASS softmax + pull aggregation (H=1), fp16 gather ------
template <int M, bool ELU, bool SPLIT>
__global__ __launch_bounds__(256) void pull_agg_sm(
    const int* __restrict__ rowptr, const int* __restrict__ csrc,
    const float* __restrict__ al_s, const float* __restrict__ al_d,
    const __half* __restrict__ h16, const float* __restrict__ bias,
    float* __restrict__ out, unsigned short* __restrict__ outHi,
    unsigned short* __restrict__ outLo) {
  constexpr int EPL = (M + 63) / 64;
  const int w = threadIdx.x >> 6;
  const int lane = threadIdx.x & 63;
  const int d = blockIdx.x * 4 + w;
  if (d >= NN) return;
  const int r0 = rowptr[d], r1 = rowptr[d + 1];
  const float ald = al_d[d];
  float m = al_s[d] + ald;                 // self-loop logit as softmax shift
  m = (m > 0.f) ? m : 0.2f * m;

  const int base = lane * EPL;
  float acc[EPL];
  #pragma unroll
  for (int j = 0; j < EPL; ++j) acc[j] = 0.f;
  float z = 0.f;

  for (int p = r0; p < r1; ++p) {
    int s = csrc[p];
    float v = al_s[s] + ald;               // broadcast load
    v = (v > 0.f) ? v : 0.2f * v;
    float a = __expf(v - m);
    z += a;
    const __half* hr = h16 + (size_t)s * M + base;
    if (M % 64 == 0 && EPL == 8) {
      // one 16B load = 8 halves (row stride M*2 B is 16B-aligned for M=512)
      uint4 raw = *(const uint4*)hr;
      float2 f0 = u2f2(raw.x), f1 = u2f2(raw.y);
      float2 f2 = u2f2(raw.z), f3 = u2f2(raw.w);
      acc[0] += f0.x * a; acc[1] += f0.y * a;
      acc[2] += f1.x * a; acc[3] += f1.y * a;
      acc[4] += f2.x * a; acc[5] += f2.y * a;
      acc[6] += f3.x * a; acc[7] += f3.y * a;
    } else {
      #pragma unroll
      for (int j = 0; j < EPL; ++j) {
        if ((M % 64 == 0) || (base + j < M))
          acc[j] += __half2float(hr[j]) * a;
      }
    }
  }
  const float iz = 1.0f / (z + 1e-16f);

  #pragma unroll
  for (int j = 0; j < EPL; ++j) {
    if ((M % 64 == 0) || (base + j < M)) {
      float v = acc[j] * iz + bias[base + j];
      if (ELU) v = (v > 0.f) ? v : (__expf(v) - 1.0f);
      if (SPLIT) {
        unsigned short hh, ll;
        split_one(v, hh, ll);
        outHi[(size_t)d * M + base + j] = hh;
        outLo[(size_t)d * M + base + j] = ll;
      } else {
        out[(size_t)d * M + base + j] = v;
      }
    }
  }
}

extern "C" void kernel_launch(void* const* d_in, const int* in_sizes, int n_in,
                              void* d_out, int out_size, void* d_ws,
                              size_t ws_size, hipStream_t stream) {
  const float* x      = (const float*)d_in[0];
  const int*   ei     = (const int*)d_in[1];
  const float* W1     = (const float*)d_in[2];
  const float* a1_src = (const float*)d_in[3];
  const float* a1_dst = (const float*)d_in[4];
  const float* b1     = (const float*)d_in[5];
  const float* W2     = (const float*)d_in[6];
  const float* a2_src = (const float*)d_in[7];
  const float* a2_dst = (const float*)d_in[8];
  const float* b2     = (const float*)d_in[9];
  const float* W3     = (const float*)d_in[10];
  const float* a3_src = (const float*)d_in[11];
  const float* a3_dst = (const float*)d_in[12];
  const float* b3     = (const float*)d_in[13];
  float* out = (float*)d_out;

  const int* esrc = ei;
  const int* edst = ei + ERAW;

  // Workspace carve-up
  unsigned short* p1Hi  = (unsigned short*)d_ws;          // NN*WIDTH
  unsigned short* p1Lo  = p1Hi + (size_t)NN * WIDTH;
  unsigned short* p2Hi  = p1Lo + (size_t)NN * WIDTH;
  unsigned short* p2Lo  = p2Hi + (size_t)NN * WIDTH;
  __half*        h16    = (__half*)(p2Lo + (size_t)NN * WIDTH);  // NN*WIDTH
  unsigned short* w1hHi = (unsigned short*)(h16 + (size_t)NN * WIDTH);
  unsigned short* w1hLo = w1hHi + (size_t)HEADS * HID * HID;
  unsigned short* w2tHi = w1hLo + (size_t)HEADS * HID * HID;  // 512*512
  unsigned short* w2tLo = w2tHi + (size_t)WIDTH * WIDTH;
  unsigned short* w3tHi = w2tLo + (size_t)WIDTH * WIDTH;  // 128*512
  unsigned short* w3tLo = w3tHi + (size_t)NCLS_P * WIDTH;
  float* bufA   = (float*)(w3tLo + (size_t)NCLS_P * WIDTH);  // NN*WIDTH (h)
  float* al_s   = bufA + (size_t)NN * WIDTH;
  float* al_d   = al_s + (size_t)NN * HEADS;
  float* w1as   = al_d + (size_t)NN * HEADS;              // 50*8
  float* w1ad   = w1as + F_IN * HEADS;
  int* deg      = (int*)(w1ad + F_IN * HEADS);
  int* rowptr   = deg + NN;
  int* cnt      = rowptr + NN + 4;
  int* csrc     = cnt + NN;                               // ETOT

  // ---- build CSR by destination (once) ----
  hipMemsetAsync(deg, 0, (size_t)NN * sizeof(int), stream);
  hipMemsetAsync(cnt, 0, (size_t)NN * sizeof(int), stream);
  const int eblk = (ETOT + 255) / 256;
  count_deg<<<eblk, 256, 0, stream>>>(edst, deg);
  scan_deg<<<1, 256, 0, stream>>>(deg, rowptr);
  scatter_csr<<<eblk, 256, 0, stream>>>(esrc, edst, rowptr, cnt, csrc);

  // ---- weight prep (once) ----
  build_w1h_t<<<(HEADS * HID * HID + 255) / 256, 256, 0, stream>>>(W1, w1hHi,
                                                                   w1hLo);
  transpose_split<<<dim3(WIDTH / 32, WIDTH / 32), 256, 0, stream>>>(
      W2, w2tHi, w2tLo, WIDTH, WIDTH, WIDTH);
  transpose_split<<<dim3(WIDTH / 32, NCLS_P / 32), 256, 0, stream>>>(
      W3, w3tHi, w3tLo, WIDTH, NCLS, NCLS_P);

  const int nwblk = (NN + 3) / 4;

  // ---- Layer 1 (aggregate-x-first; single-pass softmax+agg; head GEMM) ----
  {
    fold_w1a<<<(2 * F_IN * HEADS + 255) / 256, 256, 0, stream>>>(
        W1, a1_src, a1_dst, w1as, w1ad);
    al1_kernel<<<nwblk, 256, 0, stream>>>(x, w1as, w1ad, al_s, al_d);
    agg_x_sm<<<nwblk, 256, 0, stream>>>(rowptr, csrc, al_s, al_d, x, p1Hi,
                                        p1Lo);
    gemm_l1_heads<<<dim3((NN + 127) / 128, HEADS), 256, 0, stream>>>(
        p1Hi, p1Lo, w1hHi, w1hLo, p2Hi, p2Lo, b1);
  }
  // ---- Layer 2: h2 = x1 @ W2 -> bufA fp32 + h16; softmax-agg -> P1 split --
  {
    gemm_mfma_split<<<dim3(WIDTH / 128, (NN + 127) / 128), 256, 0, stream>>>(
        p2Hi, p2Lo, w2tHi, w2tLo, bufA, h16, NN, WIDTH, WIDTH);
    compute_al<<<nwblk, 256, 0, stream>>>(bufA, a2_src, a2_dst, al_s, al_d,
                                          NN, 1, WIDTH);
    pull_agg_sm<WIDTH, true, true><<<nwblk, 256, 0, stream>>>(
        rowptr, csrc, al_s, al_d, h16, b2, nullptr, p1Hi, p1Lo);
  }
  // ---- Layer 3: h3 = x2 @ W3 -> bufA + h16; softmax-agg -> out (no ELU) ---
  {
    gemm_mfma_split<<<dim3(NCLS_P / 128, (NN + 127) / 128), 256, 0, stream>>>(
        p1Hi, p1Lo, w3tHi, w3tLo, bufA, h16, NN, WIDTH, NCLS);
    compute_al<<<nwblk, 256, 0, stream>>>(bufA, a3_src, a3_dst, al_s, al_d,
                                          NN, 1, NCLS);
    pull_agg_sm<NCLS, false, false><<<nwblk, 256, 0, stream>>>(
        rowptr, csrc, al_s, al_d, h16, b3, out, nullptr, nullptr);
  }
}